// Round 17
// baseline (284.159 us; speedup 1.0000x reference)
//
#include <hip/hip_runtime.h>
#include <math.h>

typedef __attribute__((ext_vector_type(8))) short bf16x8;
typedef __attribute__((ext_vector_type(4))) float f32x4;
typedef __attribute__((ext_vector_type(16))) float f32x16;

static __device__ __forceinline__ short f2bf(float x){
  union { float f; unsigned u; } a; a.f = x;
  unsigned r = a.u + 0x7fffu + ((a.u >> 16) & 1u);
  return (short)(r >> 16);
}

static __device__ __forceinline__ unsigned cvtpk(float lo, float hi){
  unsigned r; asm("v_cvt_pk_bf16_f32 %0, %1, %2" : "=v"(r) : "v"(lo), "v"(hi)); return r;
}

// out[i][j] = (i < IC && j < IR) ? in[j][i] : 0 ; out dims [OR][OC] (bf16)
__global__ __launch_bounds__(256) void transpose_bf16_kernel(
    const float* __restrict__ in, short* __restrict__ out,
    int IR, int IC, int OR, int OC)
{
  __shared__ float tile[32][33];
  int i0 = blockIdx.x * 32;
  int j0 = blockIdx.y * 32;
  int tx = threadIdx.x, ty = threadIdx.y;
  #pragma unroll
  for (int r = 0; r < 32; r += 8){
    int j = j0 + ty + r, i = i0 + tx;
    tile[ty + r][tx] = (j < IR && i < IC) ? in[(size_t)j * IC + i] : 0.f;
  }
  __syncthreads();
  #pragma unroll
  for (int r = 0; r < 32; r += 8){
    int oi = i0 + ty + r, oj = j0 + tx;
    if (oi < OR && oj < OC) out[(size_t)oi * OC + oj] = f2bf(tile[tx][ty + r]);
  }
}

// bf16 transpose: in [32 bh][2048][64] -> out [32 bh][64][2048]
__global__ __launch_bounds__(256) void transpose_bb_kernel(
    const short* __restrict__ in, short* __restrict__ out)
{
  __shared__ short tile[32][33];
  int bh = blockIdx.z;
  int t0 = blockIdx.x * 32;
  int d0 = blockIdx.y * 32;
  int tx = threadIdx.x, ty = threadIdx.y;
  const short* src = in + ((size_t)bh * 2048 + t0) * 64 + d0;
  #pragma unroll
  for (int r = 0; r < 32; r += 8)
    tile[ty + r][tx] = src[(size_t)(ty + r) * 64 + tx];
  __syncthreads();
  short* dst = out + ((size_t)bh * 64 + d0) * 2048 + t0;
  #pragma unroll
  for (int r = 0; r < 32; r += 8)
    dst[(size_t)(ty + r) * 2048 + tx] = tile[tx][ty + r];
}

// one block per row of 1024; h = x / (sqrt(mean(x^2)) + eps) * g  -> bf16
__global__ __launch_bounds__(256) void rmsnorm_kernel(
    const float* __restrict__ x, const float* __restrict__ g, short* __restrict__ out)
{
  int row = blockIdx.x, tid = threadIdx.x;
  const float4* xr = (const float4*)(x + (size_t)row * 1024);
  float4 v = xr[tid];
  float ss = v.x*v.x + v.y*v.y + v.z*v.z + v.w*v.w;
  #pragma unroll
  for (int m = 1; m < 64; m <<= 1) ss += __shfl_xor(ss, m, 64);
  __shared__ float sm[4];
  if ((tid & 63) == 0) sm[tid >> 6] = ss;
  __syncthreads();
  float tot = sm[0] + sm[1] + sm[2] + sm[3];
  float inv = 1.f / (sqrtf(tot * (1.f/1024.f)) + 1e-5f);
  float4 gv = ((const float4*)g)[tid];
  short4 o;
  o.x = f2bf(v.x * inv * gv.x);
  o.y = f2bf(v.y * inv * gv.y);
  o.z = f2bf(v.z * inv * gv.z);
  o.w = f2bf(v.w * inv * gv.w);
  *(short4*)(out + (size_t)row * 1024 + tid * 4) = o;
}

enum { EPI_F32 = 0, EPI_RESID = 1, EPI_QKV = 2 };

// ---------------- deep-pipeline GEMM template ------------------------------
template<int BM, int BN>
static __device__ __forceinline__ void dp_issue(
    const short* __restrict__ A, const short* __restrict__ Bt,
    short* __restrict__ lbuf, int K, int m0, int n0, int k0,
    int wave, int lane, int l)
{
  int g = (l * 8 + wave) * 64 + lane;
  const short* src;
  if (g < BM * 8){
    int row = g >> 3, cc = g & 7;
    src = A + (size_t)(m0 + row) * K + k0 + ((cc ^ (row & 7)) << 3);
  } else {
    int gb = g - BM * 8;
    int row = gb >> 3, cc = gb & 7;
    src = Bt + (size_t)(n0 + row) * K + k0 + ((cc ^ (row & 7)) << 3);
  }
  __builtin_amdgcn_global_load_lds((const __attribute__((address_space(1))) void*)src,
                                   (__attribute__((address_space(3))) void*)(lbuf + (size_t)g * 8),
                                   16, 0, 0);
}

template<int BM, int BN, int EPI>
__global__ __launch_bounds__(512, 2) void gemm_dp_kernel(
    const short* __restrict__ A, const short* __restrict__ Bt,
    int M, int N, int K,
    float* __restrict__ outF, short* __restrict__ outB,
    const float* __restrict__ resid,
    short* __restrict__ qb, short* __restrict__ kb, short* __restrict__ vb)
{
  constexpr int L  = (BM + BN) / 64;
  constexpr int WM = BM / 2, WN = BN / 4;
  constexpr int FR = WM / 16, FC = WN / 16;
  __shared__ short lds[2][(BM + BN) * 64];
  const int tid = threadIdx.x, lane = tid & 63, wave = tid >> 6;
  const int wr = wave >> 2, wc = wave & 3;
  const int la = lane & 15, lg = lane >> 4;

  int nbn = N / BN;
  int nwg = (M / BM) * nbn;
  int bid = blockIdx.x;
  int wg = ((nwg & 7) == 0) ? ((bid & 7) * (nwg >> 3) + (bid >> 3)) : bid;  // XCD swizzle
  int m0 = (wg / nbn) * BM, n0 = (wg % nbn) * BN;

  f32x4 acc[FR][FC];
  #pragma unroll
  for (int i = 0; i < FR; ++i)
    #pragma unroll
    for (int j = 0; j < FC; ++j) acc[i][j] = f32x4{0.f, 0.f, 0.f, 0.f};

  const int NT = K >> 6;

  #pragma unroll
  for (int l = 0; l < L; ++l) dp_issue<BM, BN>(A, Bt, lds[0], K, m0, n0, 0,  wave, lane, l);
  #pragma unroll
  for (int l = 0; l < L; ++l) dp_issue<BM, BN>(A, Bt, lds[1], K, m0, n0, 64, wave, lane, l);

  for (int t = 0; t < NT; ++t){
    short* curb = lds[t & 1];
    if (t + 1 < NT){
      if constexpr (L == 8)      asm volatile("s_waitcnt vmcnt(8)" ::: "memory");
      else if constexpr (L == 6) asm volatile("s_waitcnt vmcnt(6)" ::: "memory");
      else                       asm volatile("s_waitcnt vmcnt(4)" ::: "memory");
    } else {
      asm volatile("s_waitcnt vmcnt(0)" ::: "memory");
    }
    __builtin_amdgcn_s_barrier();
    __builtin_amdgcn_sched_barrier(0);

    #pragma unroll
    for (int qr = 0; qr < FR / 4; ++qr){
      #pragma unroll
      for (int qc = 0; qc < FC / 2; ++qc){
        bf16x8 af[4][2], bfv[2][2];
        #pragma unroll
        for (int ii = 0; ii < 4; ++ii){
          int r = wr * WM + (qr * 4 + ii) * 16 + la;
          #pragma unroll
          for (int ks = 0; ks < 2; ++ks)
            af[ii][ks] = *(const bf16x8*)(curb + r * 64 + (((ks * 4 + lg) ^ (r & 7)) << 3));
        }
        #pragma unroll
        for (int jc = 0; jc < 2; ++jc){
          int rb = wc * WN + (qc * 2 + jc) * 16 + la;
          #pragma unroll
          for (int ks = 0; ks < 2; ++ks)
            bfv[jc][ks] = *(const bf16x8*)(curb + BM * 64 + rb * 64 + (((ks * 4 + lg) ^ (rb & 7)) << 3));
        }
        __builtin_amdgcn_s_setprio(1);
        #pragma unroll
        for (int ii = 0; ii < 4; ++ii)
          #pragma unroll
          for (int jc = 0; jc < 2; ++jc){
            acc[qr*4+ii][qc*2+jc] = __builtin_amdgcn_mfma_f32_16x16x32_bf16(
                af[ii][0], bfv[jc][0], acc[qr*4+ii][qc*2+jc], 0, 0, 0);
            acc[qr*4+ii][qc*2+jc] = __builtin_amdgcn_mfma_f32_16x16x32_bf16(
                af[ii][1], bfv[jc][1], acc[qr*4+ii][qc*2+jc], 0, 0, 0);
          }
        __builtin_amdgcn_s_setprio(0);
      }
    }
    __builtin_amdgcn_sched_barrier(0);
    __builtin_amdgcn_s_barrier();
    __builtin_amdgcn_sched_barrier(0);
    if (t + 2 < NT){
      #pragma unroll
      for (int l = 0; l < L; ++l)
        dp_issue<BM, BN>(A, Bt, curb, K, m0, n0, (t + 2) << 6, wave, lane, l);
    }
  }

  #pragma unroll
  for (int i = 0; i < FR; ++i){
    #pragma unroll
    for (int j = 0; j < FC; ++j){
      #pragma unroll
      for (int rr = 0; rr < 4; ++rr){
        int row = m0 + wr * WM + i * 16 + lg * 4 + rr;
        int col = n0 + wc * WN + j * 16 + la;
        float v = acc[i][j][rr];
        size_t idx = (size_t)row * N + col;
        if (EPI == EPI_F32){
          outF[idx] = v;
        } else if (EPI == EPI_RESID){
          outF[idx] = v + resid[idx];
        } else { // EPI_QKV: q scaled by (1/32)*log2(e) for exp2-domain softmax
          int which = col >> 10;
          int hh = (col & 1023) >> 6;
          int d = col & 63;
          int bb = row >> 11, tt = row & 2047;
          size_t o = (((size_t)(bb * 16 + hh) * 2048) + tt) * 64 + d;
          if (which == 0)      qb[o] = f2bf(v * 0.045084220f);
          else if (which == 1) kb[o] = f2bf(v);
          else                 vb[o] = f2bf(v);
        }
      }
    }
  }
}

// ---------------- fused W&V GEMM + SwiGLU gate -----------------------------
static __device__ __forceinline__ void wv_issue(
    const short* __restrict__ A, const short* __restrict__ Bw, const short* __restrict__ Bv,
    short* __restrict__ lbuf, int K, int m0, int n0, int k0,
    int wave, int lane, int l)
{
  int g = (l * 8 + wave) * 64 + lane;     // 0..3071
  const short* src;
  if (g < 1024){
    int row = g >> 3, cc = g & 7;
    src = A + (size_t)(m0 + row) * K + k0 + ((cc ^ (row & 7)) << 3);
  } else if (g < 2048){
    int gb = g - 1024;
    int row = gb >> 3, cc = gb & 7;
    src = Bw + (size_t)(n0 + row) * K + k0 + ((cc ^ (row & 7)) << 3);
  } else {
    int gb = g - 2048;
    int row = gb >> 3, cc = gb & 7;
    src = Bv + (size_t)(n0 + row) * K + k0 + ((cc ^ (row & 7)) << 3);
  }
  __builtin_amdgcn_global_load_lds((const __attribute__((address_space(1))) void*)src,
                                   (__attribute__((address_space(3))) void*)(lbuf + (size_t)g * 8),
                                   16, 0, 0);
}

__global__ __launch_bounds__(512, 2) void gemm_wv_kernel(
    const short* __restrict__ A, const short* __restrict__ Bw, const short* __restrict__ Bv,
    int M, int N, int K, short* __restrict__ outGated)
{
  __shared__ short lds[2][384 * 64];
  const int tid = threadIdx.x, lane = tid & 63, wave = tid >> 6;
  const int wr = wave >> 2, wc = wave & 3;
  const int la = lane & 15, lg = lane >> 4;

  int nbn = N >> 7;
  int nwg = (M >> 7) * nbn;
  int bid = blockIdx.x;
  int wg = ((nwg & 7) == 0) ? ((bid & 7) * (nwg >> 3) + (bid >> 3)) : bid;
  int m0 = (wg / nbn) << 7, n0 = (wg % nbn) << 7;

  f32x4 accW[4][2], accV[4][2];
  #pragma unroll
  for (int i = 0; i < 4; ++i)
    #pragma unroll
    for (int j = 0; j < 2; ++j){
      accW[i][j] = f32x4{0.f, 0.f, 0.f, 0.f};
      accV[i][j] = f32x4{0.f, 0.f, 0.f, 0.f};
    }

  const int NT = K >> 6;

  #pragma unroll
  for (int l = 0; l < 6; ++l) wv_issue(A, Bw, Bv, lds[0], K, m0, n0, 0,  wave, lane, l);
  #pragma unroll
  for (int l = 0; l < 6; ++l) wv_issue(A, Bw, Bv, lds[1], K, m0, n0, 64, wave, lane, l);

  for (int t = 0; t < NT; ++t){
    short* curb = lds[t & 1];
    if (t + 1 < NT) asm volatile("s_waitcnt vmcnt(6)" ::: "memory");
    else            asm volatile("s_waitcnt vmcnt(0)" ::: "memory");
    __builtin_amdgcn_s_barrier();
    __builtin_amdgcn_sched_barrier(0);

    bf16x8 af[4][2], bw[2][2], bv[2][2];
    #pragma unroll
    for (int ii = 0; ii < 4; ++ii){
      int r = wr * 64 + ii * 16 + la;
      #pragma unroll
      for (int ks = 0; ks < 2; ++ks)
        af[ii][ks] = *(const bf16x8*)(curb + r * 64 + (((ks * 4 + lg) ^ (r & 7)) << 3));
    }
    #pragma unroll
    for (int jc = 0; jc < 2; ++jc){
      int rb = wc * 32 + jc * 16 + la;
      #pragma unroll
      for (int ks = 0; ks < 2; ++ks){
        bw[jc][ks] = *(const bf16x8*)(curb +  8192 + rb * 64 + (((ks * 4 + lg) ^ (rb & 7)) << 3));
        bv[jc][ks] = *(const bf16x8*)(curb + 16384 + rb * 64 + (((ks * 4 + lg) ^ (rb & 7)) << 3));
      }
    }
    __builtin_amdgcn_s_setprio(1);
    #pragma unroll
    for (int ii = 0; ii < 4; ++ii)
      #pragma unroll
      for (int jc = 0; jc < 2; ++jc){
        accW[ii][jc] = __builtin_amdgcn_mfma_f32_16x16x32_bf16(af[ii][0], bw[jc][0], accW[ii][jc], 0, 0, 0);
        accW[ii][jc] = __builtin_amdgcn_mfma_f32_16x16x32_bf16(af[ii][1], bw[jc][1], accW[ii][jc], 0, 0, 0);
        accV[ii][jc] = __builtin_amdgcn_mfma_f32_16x16x32_bf16(af[ii][0], bv[jc][0], accV[ii][jc], 0, 0, 0);
        accV[ii][jc] = __builtin_amdgcn_mfma_f32_16x16x32_bf16(af[ii][1], bv[jc][1], accV[ii][jc], 0, 0, 0);
      }
    __builtin_amdgcn_s_setprio(0);
    __builtin_amdgcn_sched_barrier(0);
    __builtin_amdgcn_s_barrier();
    __builtin_amdgcn_sched_barrier(0);
    if (t + 2 < NT){
      #pragma unroll
      for (int l = 0; l < 6; ++l)
        wv_issue(A, Bw, Bv, curb, K, m0, n0, (t + 2) << 6, wave, lane, l);
    }
  }

  #pragma unroll
  for (int i = 0; i < 4; ++i){
    #pragma unroll
    for (int j = 0; j < 2; ++j){
      #pragma unroll
      for (int rr = 0; rr < 4; ++rr){
        int row = m0 + wr * 64 + i * 16 + lg * 4 + rr;
        int col = n0 + wc * 32 + j * 16 + la;
        float gg = accW[i][j][rr];
        float vv = accV[i][j][rr];
        float s = gg / (1.f + __expf(-gg));
        outGated[(size_t)row * N + col] = f2bf(s * vv);
      }
    }
  }
}

// ---------------- flash attention: split-pair, 2 blocks/CU -----------------
// R16 inner code unchanged. Grid 512: each block handles ONE q-tile j
// (id<256 -> heavy j=63-(id>>3)&31; id>=256 -> light j=(id>>3)&31), so the
// likely wrap-around co-resident pair (c, c+256) sums to 65 units -> 4
// waves/SIMD with balanced work. Worst-case pairing degenerates to R16's
// 2-wave overlap (no worse). 8 waves = 4 bh-slots x 2 kv-parities,
// diagonal-first kv, intra-block 2-way merge.

#define CBASE(r) ((float)(((r) & 3) + 8 * ((r) >> 2)))
#define CBI(r)   ((((r) & 3) + 8 * ((r) >> 2)))

#define KVLOAD(KF, VF, T_)                                                      \
  do {                                                                          \
    _Pragma("unroll")                                                           \
    for (int ks = 0; ks < 4; ++ks)                                              \
      KF[ks] = *(const bf16x8*)(Kg + ((size_t)((T_) * 32 + q32)) * 64 + ks * 16 + hi * 8); \
    _Pragma("unroll")                                                           \
    for (int dk = 0; dk < 4; ++dk)                                              \
      VF[dk] = *(const bf16x8*)(Vt + ((size_t)((dk >> 1) * 32 + q32)) * 2048 + (T_) * 32 + (dk & 1) * 16 + hi * 8); \
  } while (0)

#define PROC(CK, CV, T_, DOPF, NK, NV)                                          \
  do {                                                                          \
    f32x16 sS;                                                                  \
    _Pragma("unroll") for (int i = 0; i < 16; ++i) sS[i] = 0.f;                 \
    sS = __builtin_amdgcn_mfma_f32_32x32x16_bf16(CK[0], qf[0], sS, 0, 0, 0);    \
    sS = __builtin_amdgcn_mfma_f32_32x32x16_bf16(CK[1], qf[1], sS, 0, 0, 0);    \
    sS = __builtin_amdgcn_mfma_f32_32x32x16_bf16(CK[2], qf[2], sS, 0, 0, 0);    \
    sS = __builtin_amdgcn_mfma_f32_32x32x16_bf16(CK[3], qf[3], sS, 0, 0, 0);    \
    if (DOPF) KVLOAD(NK, NV, (T_) - 2);                                         \
    float bb2 = slope2 * (float)((T_) * 32 + 4 * hi - qpos);                    \
    float sc[16];                                                               \
    _Pragma("unroll")                                                           \
    for (int r = 0; r < 16; ++r) sc[r] = (sS[r] + bb2) + slope2 * CBASE(r);     \
    if ((T_) == j){                                                             \
      _Pragma("unroll")                                                         \
      for (int r = 0; r < 16; ++r)                                              \
        sc[r] = (CBI(r) + 4 * hi <= q32) ? sc[r] : -1e30f;                      \
    }                                                                           \
    float t8[8], t4[4];                                                         \
    _Pragma("unroll") for (int i = 0; i < 8; ++i) t8[i] = fmaxf(sc[i], sc[i + 8]); \
    _Pragma("unroll") for (int i = 0; i < 4; ++i) t4[i] = fmaxf(t8[i], t8[i + 4]); \
    float mx = fmaxf(fmaxf(t4[0], t4[1]), fmaxf(t4[2], t4[3]));                 \
    mx = fmaxf(mx, __shfl_xor(mx, 32, 64));                                     \
    if (!__all(mx <= m_run + 8.f)){                                             \
      float mnew = fmaxf(m_run, mx);                                            \
      float aL = exp2f(m_run - mnew);                                           \
      l_run *= aL;                                                              \
      m_run = mnew;                                                             \
      _Pragma("unroll")                                                         \
      for (int r = 0; r < 16; ++r){                                             \
        float aq = __shfl(aL, CBI(r) + 4 * hi, 64);                             \
        o0[r] *= aq; o1[r] *= aq;                                               \
      }                                                                         \
    }                                                                           \
    float pr[16];                                                               \
    _Pragma("unroll")                                                           \
    for (int r = 0; r < 16; ++r) pr[r] = exp2f(sc[r] - m_run);                  \
    _Pragma("unroll") for (int i = 0; i < 8; ++i) t8[i] = pr[i] + pr[i + 8];    \
    _Pragma("unroll") for (int i = 0; i < 4; ++i) t4[i] = t8[i] + t8[i + 4];    \
    float ps = (t4[0] + t4[1]) + (t4[2] + t4[3]);                               \
    ps += __shfl_xor(ps, 32, 64);                                               \
    l_run += ps;                                                                \
    unsigned c0 = cvtpk(pr[0], pr[1]),   c1 = cvtpk(pr[2], pr[3]);              \
    unsigned c2 = cvtpk(pr[4], pr[5]),   c3 = cvtpk(pr[6], pr[7]);              \
    unsigned c4 = cvtpk(pr[8], pr[9]),   c5 = cvtpk(pr[10], pr[11]);            \
    unsigned c6 = cvtpk(pr[12], pr[13]), c7 = cvtpk(pr[14], pr[15]);            \
    unsigned x0 = (unsigned)__shfl_xor((int)c0, 32, 64), x1 = (unsigned)__shfl_xor((int)c1, 32, 64); \
    unsigned x2 = (unsigned)__shfl_xor((int)c2, 32, 64), x3 = (unsigned)__shfl_xor((int)c3, 32, 64); \
    unsigned x4 = (unsigned)__shfl_xor((int)c4, 32, 64), x5 = (unsigned)__shfl_xor((int)c5, 32, 64); \
    unsigned x6 = (unsigned)__shfl_xor((int)c6, 32, 64), x7 = (unsigned)__shfl_xor((int)c7, 32, 64); \
    union { unsigned u[4]; bf16x8 v; } pa0u, pa1u;                              \
    pa0u.u[0] = hi ? x2 : c0;  pa0u.u[1] = hi ? x3 : c1;                        \
    pa0u.u[2] = hi ? c2 : x0;  pa0u.u[3] = hi ? c3 : x1;                        \
    pa1u.u[0] = hi ? x6 : c4;  pa1u.u[1] = hi ? x7 : c5;                        \
    pa1u.u[2] = hi ? c6 : x4;  pa1u.u[3] = hi ? c7 : x5;                        \
    o0 = __builtin_amdgcn_mfma_f32_32x32x16_bf16(pa0u.v, CV[0], o0, 0, 0, 0);   \
    o0 = __builtin_amdgcn_mfma_f32_32x32x16_bf16(pa1u.v, CV[1], o0, 0, 0, 0);   \
    o1 = __builtin_amdgcn_mfma_f32_32x32x16_bf16(pa0u.v, CV[2], o1, 0, 0, 0);   \
    o1 = __builtin_amdgcn_mfma_f32_32x32x16_bf16(pa1u.v, CV[3], o1, 0, 0, 0);   \
  } while (0)

__global__ __launch_bounds__(512) void attn_kernel(
    const short* __restrict__ qb, const short* __restrict__ kb,
    const short* __restrict__ vtb, short* __restrict__ concat)
{
  const int T = 2048;
  int id = blockIdx.x;                 // 512 blocks
  int grp = id & 7;                    // XCD-ish group: bh {4*grp .. 4*grp+3}
  int q5  = (id >> 3) & 31;
  int j   = (id < 256) ? (63 - q5) : q5;   // heavy first; pair (c,c+256) sums 63
  int wid = threadIdx.x >> 6;
  int e   = wid & 3;                   // task slot (bh within group)
  int s   = wid >> 2;                  // kv parity 0/1
  int bh = grp * 4 + e;
  int lane = threadIdx.x & 63;
  int q32 = lane & 31;
  int hi  = lane >> 5;
  int h = bh & 15, b = bh >> 4;

  __shared__ float partLDS[4][16][64][2];   // [slot][r2][lane][pair] 32KB
  __shared__ float mlLDS[4][64][2];         // [slot][lane][m,l]      2KB

  const short* Q  = qb  + (size_t)bh * T * 64;
  const short* Kg = kb  + (size_t)bh * T * 64;  // [t][d]
  const short* Vt = vtb + (size_t)bh * 64 * T;  // [d][t]

  float slope2 = exp2f(-0.5f * (float)(h + 1)) * 1.44269504f;

  int q0 = j * 32;
  int qpos = q0 + q32;

  bf16x8 qf[4];
  #pragma unroll
  for (int ks = 0; ks < 4; ++ks)
    qf[ks] = *(const bf16x8*)(Q + (size_t)qpos * 64 + ks * 16 + hi * 8);

  f32x16 o0, o1;
  #pragma unroll
  for (int i = 0; i < 16; ++i){ o0[i] = 0.f; o1[i] = 0.f; }
  float m_run = -1e30f, l_run = 0.f;

  if (s <= j){
    // descending kv: start at largest tile of this parity (diagonal side)
    int t0 = j - ((j - s) & 1);
    bf16x8 kA[4], vA[4], kB[4], vB[4];
    KVLOAD(kA, vA, t0);
    int t = t0;
    while (1){
      PROC(kA, vA, t, (t - 2 >= s), kB, vB);
      t -= 2; if (t < s) break;
      PROC(kB, vB, t, (t - 2 >= s), kA, vA);
      t -= 2; if (t < s) break;
    }
  }

  if (s == 0){
    #pragma unroll
    for (int r2 = 0; r2 < 8; ++r2){
      partLDS[e][r2][lane][0]     = o0[2 * r2];
      partLDS[e][r2][lane][1]     = o0[2 * r2 + 1];
      partLDS[e][r2 + 8][lane][0] = o1[2 * r2];
      partLDS[e][r2 + 8][lane][1] = o1[2 * r2 + 1];
    }
    mlLDS[e][lane][0] = m_run;
    mlLDS[e][lane][1] = l_run;
  }
  __syncthreads();
  if (s == 1){
    float mE = mlLDS[e][lane][0];
    float lE = mlLDS[e][lane][1];
    float mS = fmaxf(mE, m_run);
    float aE = exp2f(mE - mS);
    float aO = exp2f(m_run - mS);
    float lT = aE * lE + aO * l_run;
    float linv = 1.f / lT;
    float fE = aE * linv;
    float fO = aO * linv;
    #pragma unroll
    for (int r = 0; r < 16; ++r){
      int crow = CBI(r) + 4 * hi;
      float fEr = __shfl(fE, crow, 64);
      float fOr = __shfl(fO, crow, 64);
      float oE0 = partLDS[e][r >> 1][lane][r & 1];
      float oE1 = partLDS[e][8 + (r >> 1)][lane][r & 1];
      size_t base = ((size_t)(b * 2048 + q0 + crow)) * 1024 + h * 64;
      concat[base + q32]      = f2bf(fEr * oE0 + fOr * o0[r]);
      concat[base + 32 + q32] = f2bf(fEr * oE1 + fOr * o1[r]);
    }
  }
}

extern "C" void kernel_launch(void* const* d_in, const int* in_sizes, int n_in,
                              void* d_out, int out_size, void* d_ws, size_t ws_size,
                              hipStream_t stream)
{
  (void)in_sizes; (void)n_in; (void)out_size; (void)ws_size;
  const float* x     = (const float*)d_in[0];
  const float* g1    = (const float*)d_in[1];
  const float* w_qkv = (const float*)d_in[2];
  const float* w_o   = (const float*)d_in[3];
  const float* g2    = (const float*)d_in[4];
  const float* W     = (const float*)d_in[5];
  const float* V     = (const float*)d_in[6];
  const float* W2    = (const float*)d_in[7];
  float* out = (float*)d_out;

  char* wsb = (char*)d_ws;
  size_t off = 0;
  auto alloc = [&](size_t bytes) -> void* {
    void* p = wsb + off;
    off += (bytes + 255) & ~(size_t)255;
    return p;
  };
  short* wqkvT = (short*)alloc((size_t)3072 * 1024 * 2);
  short* woT   = (short*)alloc((size_t)1024 * 1024 * 2);
  short* WT    = (short*)alloc((size_t)2816 * 1024 * 2);
  short* VT    = (short*)alloc((size_t)2816 * 1024 * 2);
  short* W2T   = (short*)alloc((size_t)1024 * 2816 * 2);
  short* h1    = (short*)alloc((size_t)4096 * 1024 * 2);
  short* qbuf  = (short*)alloc((size_t)4096 * 1024 * 2);
  short* kbuf  = (short*)alloc((size_t)4096 * 1024 * 2);
  short* vbuf  = (short*)alloc((size_t)4096 * 1024 * 2); // [B,H,T,64]
  short* vtbuf = (short*)alloc((size_t)4096 * 1024 * 2); // [B,H,64,T]
  short* conc  = (short*)alloc((size_t)4096 * 1024 * 2);
  float* x2    = (float*)alloc((size_t)4096 * 1024 * 4);
  short* h2    = (short*)alloc((size_t)4096 * 1024 * 2);
  short* gated = (short*)alloc((size_t)4096 * 2816 * 2);

  dim3 tb(32, 8);
  hipLaunchKernelGGL(transpose_bf16_kernel, dim3(96, 32), tb, 0, stream, w_qkv, wqkvT, 1024, 3072, 3072, 1024);
  hipLaunchKernelGGL(transpose_bf16_kernel, dim3(32, 32), tb, 0, stream, w_o,   woT,   1024, 1024, 1024, 1024);
  hipLaunchKernelGGL(transpose_bf16_kernel, dim3(88, 32), tb, 0, stream, W,     WT,    1024, 2728, 2816, 1024);
  hipLaunchKernelGGL(transpose_bf16_kernel, dim3(88, 32), tb, 0, stream, V,     VT,    1024, 2728, 2816, 1024);
  hipLaunchKernelGGL(transpose_bf16_kernel, dim3(32, 88), tb, 0, stream, W2,    W2T,   2728, 1024, 1024, 2816);

  hipLaunchKernelGGL(rmsnorm_kernel, dim3(4096), dim3(256), 0, stream, x, g1, h1);

  hipLaunchKernelGGL((gemm_dp_kernel<128, 128, EPI_QKV>), dim3(768), dim3(512), 0, stream,
                     h1, wqkvT, 4096, 3072, 1024,
                     (float*)nullptr, (short*)nullptr, (const float*)nullptr,
                     qbuf, kbuf, vbuf);

  hipLaunchKernelGGL(transpose_bb_kernel, dim3(64, 2, 32), tb, 0, stream, vbuf, vtbuf);

  hipLaunchKernelGGL(attn_kernel, dim3(512), dim3(512), 0, stream, qbuf, kbuf, vtbuf, conc);

  hipLaunchKernelGGL((gemm_dp_kernel<128, 128, EPI_RESID>), dim3(256), dim3(512), 0, stream,
                     conc, woT, 4096, 1024, 1024,
                     x2, (short*)nullptr, x,
                     (short*)nullptr, (short*)nullptr, (short*)nullptr);

  hipLaunchKernelGGL(rmsnorm_kernel, dim3(4096), dim3(256), 0, stream, x2, g2, h2);

  hipLaunchKernelGGL(gemm_wv_kernel, dim3(704), dim3(512), 0, stream,
                     h2, WT, VT, 4096, 2816, 1024, gated);

  hipLaunchKernelGGL((gemm_dp_kernel<128, 128, EPI_RESID>), dim3(256), dim3(512), 0, stream,
                     gated, W2T, 4096, 1024, 2816,
                     out, (short*)nullptr, x2,
                     (short*)nullptr, (short*)nullptr, (short*)nullptr);
}

// Round 18
// 265.879 us; speedup vs baseline: 1.0688x; 1.0688x over previous
//
#include <hip/hip_runtime.h>
#include <math.h>

typedef __attribute__((ext_vector_type(8))) short bf16x8;
typedef __attribute__((ext_vector_type(4))) float f32x4;
typedef __attribute__((ext_vector_type(16))) float f32x16;

static __device__ __forceinline__ short f2bf(float x){
  union { float f; unsigned u; } a; a.f = x;
  unsigned r = a.u + 0x7fffu + ((a.u >> 16) & 1u);
  return (short)(r >> 16);
}

static __device__ __forceinline__ unsigned cvtpk(float lo, float hi){
  unsigned r; asm("v_cvt_pk_bf16_f32 %0, %1, %2" : "=v"(r) : "v"(lo), "v"(hi)); return r;
}

// out[i][j] = (i < IC && j < IR) ? in[j][i] : 0 ; out dims [OR][OC] (bf16)
__global__ __launch_bounds__(256) void transpose_bf16_kernel(
    const float* __restrict__ in, short* __restrict__ out,
    int IR, int IC, int OR, int OC)
{
  __shared__ float tile[32][33];
  int i0 = blockIdx.x * 32;
  int j0 = blockIdx.y * 32;
  int tx = threadIdx.x, ty = threadIdx.y;
  #pragma unroll
  for (int r = 0; r < 32; r += 8){
    int j = j0 + ty + r, i = i0 + tx;
    tile[ty + r][tx] = (j < IR && i < IC) ? in[(size_t)j * IC + i] : 0.f;
  }
  __syncthreads();
  #pragma unroll
  for (int r = 0; r < 32; r += 8){
    int oi = i0 + ty + r, oj = j0 + tx;
    if (oi < OR && oj < OC) out[(size_t)oi * OC + oj] = f2bf(tile[tx][ty + r]);
  }
}

// bf16 transpose: in [32 bh][2048][64] -> out [32 bh][64][2048]
__global__ __launch_bounds__(256) void transpose_bb_kernel(
    const short* __restrict__ in, short* __restrict__ out)
{
  __shared__ short tile[32][33];
  int bh = blockIdx.z;
  int t0 = blockIdx.x * 32;
  int d0 = blockIdx.y * 32;
  int tx = threadIdx.x, ty = threadIdx.y;
  const short* src = in + ((size_t)bh * 2048 + t0) * 64 + d0;
  #pragma unroll
  for (int r = 0; r < 32; r += 8)
    tile[ty + r][tx] = src[(size_t)(ty + r) * 64 + tx];
  __syncthreads();
  short* dst = out + ((size_t)bh * 64 + d0) * 2048 + t0;
  #pragma unroll
  for (int r = 0; r < 32; r += 8)
    dst[(size_t)(ty + r) * 2048 + tx] = tile[tx][ty + r];
}

// one block per row of 1024; h = x / (sqrt(mean(x^2)) + eps) * g  -> bf16
__global__ __launch_bounds__(256) void rmsnorm_kernel(
    const float* __restrict__ x, const float* __restrict__ g, short* __restrict__ out)
{
  int row = blockIdx.x, tid = threadIdx.x;
  const float4* xr = (const float4*)(x + (size_t)row * 1024);
  float4 v = xr[tid];
  float ss = v.x*v.x + v.y*v.y + v.z*v.z + v.w*v.w;
  #pragma unroll
  for (int m = 1; m < 64; m <<= 1) ss += __shfl_xor(ss, m, 64);
  __shared__ float sm[4];
  if ((tid & 63) == 0) sm[tid >> 6] = ss;
  __syncthreads();
  float tot = sm[0] + sm[1] + sm[2] + sm[3];
  float inv = 1.f / (sqrtf(tot * (1.f/1024.f)) + 1e-5f);
  float4 gv = ((const float4*)g)[tid];
  short4 o;
  o.x = f2bf(v.x * inv * gv.x);
  o.y = f2bf(v.y * inv * gv.y);
  o.z = f2bf(v.z * inv * gv.z);
  o.w = f2bf(v.w * inv * gv.w);
  *(short4*)(out + (size_t)row * 1024 + tid * 4) = o;
}

enum { EPI_F32 = 0, EPI_RESID = 1, EPI_QKV = 2 };

// ---------------- deep-pipeline GEMM template ------------------------------
template<int BM, int BN>
static __device__ __forceinline__ void dp_issue(
    const short* __restrict__ A, const short* __restrict__ Bt,
    short* __restrict__ lbuf, int K, int m0, int n0, int k0,
    int wave, int lane, int l)
{
  int g = (l * 8 + wave) * 64 + lane;
  const short* src;
  if (g < BM * 8){
    int row = g >> 3, cc = g & 7;
    src = A + (size_t)(m0 + row) * K + k0 + ((cc ^ (row & 7)) << 3);
  } else {
    int gb = g - BM * 8;
    int row = gb >> 3, cc = gb & 7;
    src = Bt + (size_t)(n0 + row) * K + k0 + ((cc ^ (row & 7)) << 3);
  }
  __builtin_amdgcn_global_load_lds((const __attribute__((address_space(1))) void*)src,
                                   (__attribute__((address_space(3))) void*)(lbuf + (size_t)g * 8),
                                   16, 0, 0);
}

template<int BM, int BN, int EPI>
__global__ __launch_bounds__(512, 2) void gemm_dp_kernel(
    const short* __restrict__ A, const short* __restrict__ Bt,
    int M, int N, int K,
    float* __restrict__ outF, short* __restrict__ outB,
    const float* __restrict__ resid,
    short* __restrict__ qb, short* __restrict__ kb, short* __restrict__ vb)
{
  constexpr int L  = (BM + BN) / 64;
  constexpr int WM = BM / 2, WN = BN / 4;
  constexpr int FR = WM / 16, FC = WN / 16;
  __shared__ short lds[2][(BM + BN) * 64];
  const int tid = threadIdx.x, lane = tid & 63, wave = tid >> 6;
  const int wr = wave >> 2, wc = wave & 3;
  const int la = lane & 15, lg = lane >> 4;

  int nbn = N / BN;
  int nwg = (M / BM) * nbn;
  int bid = blockIdx.x;
  int wg = ((nwg & 7) == 0) ? ((bid & 7) * (nwg >> 3) + (bid >> 3)) : bid;  // XCD swizzle
  int m0 = (wg / nbn) * BM, n0 = (wg % nbn) * BN;

  f32x4 acc[FR][FC];
  #pragma unroll
  for (int i = 0; i < FR; ++i)
    #pragma unroll
    for (int j = 0; j < FC; ++j) acc[i][j] = f32x4{0.f, 0.f, 0.f, 0.f};

  const int NT = K >> 6;

  #pragma unroll
  for (int l = 0; l < L; ++l) dp_issue<BM, BN>(A, Bt, lds[0], K, m0, n0, 0,  wave, lane, l);
  #pragma unroll
  for (int l = 0; l < L; ++l) dp_issue<BM, BN>(A, Bt, lds[1], K, m0, n0, 64, wave, lane, l);

  for (int t = 0; t < NT; ++t){
    short* curb = lds[t & 1];
    if (t + 1 < NT){
      if constexpr (L == 8)      asm volatile("s_waitcnt vmcnt(8)" ::: "memory");
      else if constexpr (L == 6) asm volatile("s_waitcnt vmcnt(6)" ::: "memory");
      else                       asm volatile("s_waitcnt vmcnt(4)" ::: "memory");
    } else {
      asm volatile("s_waitcnt vmcnt(0)" ::: "memory");
    }
    __builtin_amdgcn_s_barrier();
    __builtin_amdgcn_sched_barrier(0);

    #pragma unroll
    for (int qr = 0; qr < FR / 4; ++qr){
      #pragma unroll
      for (int qc = 0; qc < FC / 2; ++qc){
        bf16x8 af[4][2], bfv[2][2];
        #pragma unroll
        for (int ii = 0; ii < 4; ++ii){
          int r = wr * WM + (qr * 4 + ii) * 16 + la;
          #pragma unroll
          for (int ks = 0; ks < 2; ++ks)
            af[ii][ks] = *(const bf16x8*)(curb + r * 64 + (((ks * 4 + lg) ^ (r & 7)) << 3));
        }
        #pragma unroll
        for (int jc = 0; jc < 2; ++jc){
          int rb = wc * WN + (qc * 2 + jc) * 16 + la;
          #pragma unroll
          for (int ks = 0; ks < 2; ++ks)
            bfv[jc][ks] = *(const bf16x8*)(curb + BM * 64 + rb * 64 + (((ks * 4 + lg) ^ (rb & 7)) << 3));
        }
        __builtin_amdgcn_s_setprio(1);
        #pragma unroll
        for (int ii = 0; ii < 4; ++ii)
          #pragma unroll
          for (int jc = 0; jc < 2; ++jc){
            acc[qr*4+ii][qc*2+jc] = __builtin_amdgcn_mfma_f32_16x16x32_bf16(
                af[ii][0], bfv[jc][0], acc[qr*4+ii][qc*2+jc], 0, 0, 0);
            acc[qr*4+ii][qc*2+jc] = __builtin_amdgcn_mfma_f32_16x16x32_bf16(
                af[ii][1], bfv[jc][1], acc[qr*4+ii][qc*2+jc], 0, 0, 0);
          }
        __builtin_amdgcn_s_setprio(0);
      }
    }
    __builtin_amdgcn_sched_barrier(0);
    __builtin_amdgcn_s_barrier();
    __builtin_amdgcn_sched_barrier(0);
    if (t + 2 < NT){
      #pragma unroll
      for (int l = 0; l < L; ++l)
        dp_issue<BM, BN>(A, Bt, curb, K, m0, n0, (t + 2) << 6, wave, lane, l);
    }
  }

  #pragma unroll
  for (int i = 0; i < FR; ++i){
    #pragma unroll
    for (int j = 0; j < FC; ++j){
      #pragma unroll
      for (int rr = 0; rr < 4; ++rr){
        int row = m0 + wr * WM + i * 16 + lg * 4 + rr;
        int col = n0 + wc * WN + j * 16 + la;
        float v = acc[i][j][rr];
        size_t idx = (size_t)row * N + col;
        if (EPI == EPI_F32){
          outF[idx] = v;
        } else if (EPI == EPI_RESID){
          outF[idx] = v + resid[idx];
        } else { // EPI_QKV: q scaled by (1/32)*log2(e) for exp2-domain softmax
          int which = col >> 10;
          int hh = (col & 1023) >> 6;
          int d = col & 63;
          int bb = row >> 11, tt = row & 2047;
          size_t o = (((size_t)(bb * 16 + hh) * 2048) + tt) * 64 + d;
          if (which == 0)      qb[o] = f2bf(v * 0.045084220f);
          else if (which == 1) kb[o] = f2bf(v);
          else                 vb[o] = f2bf(v);
        }
      }
    }
  }
}

// ---------------- fused W&V GEMM + SwiGLU gate -----------------------------
static __device__ __forceinline__ void wv_issue(
    const short* __restrict__ A, const short* __restrict__ Bw, const short* __restrict__ Bv,
    short* __restrict__ lbuf, int K, int m0, int n0, int k0,
    int wave, int lane, int l)
{
  int g = (l * 8 + wave) * 64 + lane;     // 0..3071
  const short* src;
  if (g < 1024){
    int row = g >> 3, cc = g & 7;
    src = A + (size_t)(m0 + row) * K + k0 + ((cc ^ (row & 7)) << 3);
  } else if (g < 2048){
    int gb = g - 1024;
    int row = gb >> 3, cc = gb & 7;
    src = Bw + (size_t)(n0 + row) * K + k0 + ((cc ^ (row & 7)) << 3);
  } else {
    int gb = g - 2048;
    int row = gb >> 3, cc = gb & 7;
    src = Bv + (size_t)(n0 + row) * K + k0 + ((cc ^ (row & 7)) << 3);
  }
  __builtin_amdgcn_global_load_lds((const __attribute__((address_space(1))) void*)src,
                                   (__attribute__((address_space(3))) void*)(lbuf + (size_t)g * 8),
                                   16, 0, 0);
}

__global__ __launch_bounds__(512, 2) void gemm_wv_kernel(
    const short* __restrict__ A, const short* __restrict__ Bw, const short* __restrict__ Bv,
    int M, int N, int K, short* __restrict__ outGated)
{
  __shared__ short lds[2][384 * 64];
  const int tid = threadIdx.x, lane = tid & 63, wave = tid >> 6;
  const int wr = wave >> 2, wc = wave & 3;
  const int la = lane & 15, lg = lane >> 4;

  int nbn = N >> 7;
  int nwg = (M >> 7) * nbn;
  int bid = blockIdx.x;
  int wg = ((nwg & 7) == 0) ? ((bid & 7) * (nwg >> 3) + (bid >> 3)) : bid;
  int m0 = (wg / nbn) << 7, n0 = (wg % nbn) << 7;

  f32x4 accW[4][2], accV[4][2];
  #pragma unroll
  for (int i = 0; i < 4; ++i)
    #pragma unroll
    for (int j = 0; j < 2; ++j){
      accW[i][j] = f32x4{0.f, 0.f, 0.f, 0.f};
      accV[i][j] = f32x4{0.f, 0.f, 0.f, 0.f};
    }

  const int NT = K >> 6;

  #pragma unroll
  for (int l = 0; l < 6; ++l) wv_issue(A, Bw, Bv, lds[0], K, m0, n0, 0,  wave, lane, l);
  #pragma unroll
  for (int l = 0; l < 6; ++l) wv_issue(A, Bw, Bv, lds[1], K, m0, n0, 64, wave, lane, l);

  for (int t = 0; t < NT; ++t){
    short* curb = lds[t & 1];
    if (t + 1 < NT) asm volatile("s_waitcnt vmcnt(6)" ::: "memory");
    else            asm volatile("s_waitcnt vmcnt(0)" ::: "memory");
    __builtin_amdgcn_s_barrier();
    __builtin_amdgcn_sched_barrier(0);

    bf16x8 af[4][2], bw[2][2], bv[2][2];
    #pragma unroll
    for (int ii = 0; ii < 4; ++ii){
      int r = wr * 64 + ii * 16 + la;
      #pragma unroll
      for (int ks = 0; ks < 2; ++ks)
        af[ii][ks] = *(const bf16x8*)(curb + r * 64 + (((ks * 4 + lg) ^ (r & 7)) << 3));
    }
    #pragma unroll
    for (int jc = 0; jc < 2; ++jc){
      int rb = wc * 32 + jc * 16 + la;
      #pragma unroll
      for (int ks = 0; ks < 2; ++ks){
        bw[jc][ks] = *(const bf16x8*)(curb +  8192 + rb * 64 + (((ks * 4 + lg) ^ (rb & 7)) << 3));
        bv[jc][ks] = *(const bf16x8*)(curb + 16384 + rb * 64 + (((ks * 4 + lg) ^ (rb & 7)) << 3));
      }
    }
    __builtin_amdgcn_s_setprio(1);
    #pragma unroll
    for (int ii = 0; ii < 4; ++ii)
      #pragma unroll
      for (int jc = 0; jc < 2; ++jc){
        accW[ii][jc] = __builtin_amdgcn_mfma_f32_16x16x32_bf16(af[ii][0], bw[jc][0], accW[ii][jc], 0, 0, 0);
        accW[ii][jc] = __builtin_amdgcn_mfma_f32_16x16x32_bf16(af[ii][1], bw[jc][1], accW[ii][jc], 0, 0, 0);
        accV[ii][jc] = __builtin_amdgcn_mfma_f32_16x16x32_bf16(af[ii][0], bv[jc][0], accV[ii][jc], 0, 0, 0);
        accV[ii][jc] = __builtin_amdgcn_mfma_f32_16x16x32_bf16(af[ii][1], bv[jc][1], accV[ii][jc], 0, 0, 0);
      }
    __builtin_amdgcn_s_setprio(0);
    __builtin_amdgcn_sched_barrier(0);
    __builtin_amdgcn_s_barrier();
    __builtin_amdgcn_sched_barrier(0);
    if (t + 2 < NT){
      #pragma unroll
      for (int l = 0; l < 6; ++l)
        wv_issue(A, Bw, Bv, curb, K, m0, n0, (t + 2) << 6, wave, lane, l);
    }
  }

  #pragma unroll
  for (int i = 0; i < 4; ++i){
    #pragma unroll
    for (int j = 0; j < 2; ++j){
      #pragma unroll
      for (int rr = 0; rr < 4; ++rr){
        int row = m0 + wr * 64 + i * 16 + lg * 4 + rr;
        int col = n0 + wc * 32 + j * 16 + la;
        float gg = accW[i][j][rr];
        float vv = accV[i][j][rr];
        float s = gg / (1.f + __expf(-gg));
        outGated[(size_t)row * N + col] = f2bf(s * vv);
      }
    }
  }
}

// ---------------- flash attention: R16 structure, DIAGONAL-FIRST kv --------
// Block = 512 thr = 8 waves = 4 bh-slots x 2 kv-parities; q-pair (p, 63-p)
// -> every block exactly 65 tile-units (dispatch-order-proof balance).
// Descending kv (diagonal first) keeps defer-max (THR=8) active. Intra-block
// 2-way merge via LDS. shfl_xor softmax (proven).

#define CBASE(r) ((float)(((r) & 3) + 8 * ((r) >> 2)))
#define CBI(r)   ((((r) & 3) + 8 * ((r) >> 2)))

#define KVLOAD(KF, VF, T_)                                                      \
  do {                                                                          \
    _Pragma("unroll")                                                           \
    for (int ks = 0; ks < 4; ++ks)                                              \
      KF[ks] = *(const bf16x8*)(Kg + ((size_t)((T_) * 32 + q32)) * 64 + ks * 16 + hi * 8); \
    _Pragma("unroll")                                                           \
    for (int dk = 0; dk < 4; ++dk)                                              \
      VF[dk] = *(const bf16x8*)(Vt + ((size_t)((dk >> 1) * 32 + q32)) * 2048 + (T_) * 32 + (dk & 1) * 16 + hi * 8); \
  } while (0)

#define PROC(CK, CV, T_, DOPF, NK, NV)                                          \
  do {                                                                          \
    f32x16 sS;                                                                  \
    _Pragma("unroll") for (int i = 0; i < 16; ++i) sS[i] = 0.f;                 \
    sS = __builtin_amdgcn_mfma_f32_32x32x16_bf16(CK[0], qf[0], sS, 0, 0, 0);    \
    sS = __builtin_amdgcn_mfma_f32_32x32x16_bf16(CK[1], qf[1], sS, 0, 0, 0);    \
    sS = __builtin_amdgcn_mfma_f32_32x32x16_bf16(CK[2], qf[2], sS, 0, 0, 0);    \
    sS = __builtin_amdgcn_mfma_f32_32x32x16_bf16(CK[3], qf[3], sS, 0, 0, 0);    \
    if (DOPF) KVLOAD(NK, NV, (T_) - 2);                                         \
    float bb2 = slope2 * (float)((T_) * 32 + 4 * hi - qpos);                    \
    float sc[16];                                                               \
    _Pragma("unroll")                                                           \
    for (int r = 0; r < 16; ++r) sc[r] = (sS[r] + bb2) + slope2 * CBASE(r);     \
    if ((T_) == j){                                                             \
      _Pragma("unroll")                                                         \
      for (int r = 0; r < 16; ++r)                                              \
        sc[r] = (CBI(r) + 4 * hi <= q32) ? sc[r] : -1e30f;                      \
    }                                                                           \
    float t8[8], t4[4];                                                         \
    _Pragma("unroll") for (int i = 0; i < 8; ++i) t8[i] = fmaxf(sc[i], sc[i + 8]); \
    _Pragma("unroll") for (int i = 0; i < 4; ++i) t4[i] = fmaxf(t8[i], t8[i + 4]); \
    float mx = fmaxf(fmaxf(t4[0], t4[1]), fmaxf(t4[2], t4[3]));                 \
    mx = fmaxf(mx, __shfl_xor(mx, 32, 64));                                     \
    if (!__all(mx <= m_run + 8.f)){                                             \
      float mnew = fmaxf(m_run, mx);                                            \
      float aL = exp2f(m_run - mnew);                                           \
      l_run *= aL;                                                              \
      m_run = mnew;                                                             \
      _Pragma("unroll")                                                         \
      for (int r = 0; r < 16; ++r){                                             \
        float aq = __shfl(aL, CBI(r) + 4 * hi, 64);                             \
        o0[r] *= aq; o1[r] *= aq;                                               \
      }                                                                         \
    }                                                                           \
    float pr[16];                                                               \
    _Pragma("unroll")                                                           \
    for (int r = 0; r < 16; ++r) pr[r] = exp2f(sc[r] - m_run);                  \
    _Pragma("unroll") for (int i = 0; i < 8; ++i) t8[i] = pr[i] + pr[i + 8];    \
    _Pragma("unroll") for (int i = 0; i < 4; ++i) t4[i] = t8[i] + t8[i + 4];    \
    float ps = (t4[0] + t4[1]) + (t4[2] + t4[3]);                               \
    ps += __shfl_xor(ps, 32, 64);                                               \
    l_run += ps;                                                                \
    unsigned c0 = cvtpk(pr[0], pr[1]),   c1 = cvtpk(pr[2], pr[3]);              \
    unsigned c2 = cvtpk(pr[4], pr[5]),   c3 = cvtpk(pr[6], pr[7]);              \
    unsigned c4 = cvtpk(pr[8], pr[9]),   c5 = cvtpk(pr[10], pr[11]);            \
    unsigned c6 = cvtpk(pr[12], pr[13]), c7 = cvtpk(pr[14], pr[15]);            \
    unsigned x0 = (unsigned)__shfl_xor((int)c0, 32, 64), x1 = (unsigned)__shfl_xor((int)c1, 32, 64); \
    unsigned x2 = (unsigned)__shfl_xor((int)c2, 32, 64), x3 = (unsigned)__shfl_xor((int)c3, 32, 64); \
    unsigned x4 = (unsigned)__shfl_xor((int)c4, 32, 64), x5 = (unsigned)__shfl_xor((int)c5, 32, 64); \
    unsigned x6 = (unsigned)__shfl_xor((int)c6, 32, 64), x7 = (unsigned)__shfl_xor((int)c7, 32, 64); \
    union { unsigned u[4]; bf16x8 v; } pa0u, pa1u;                              \
    pa0u.u[0] = hi ? x2 : c0;  pa0u.u[1] = hi ? x3 : c1;                        \
    pa0u.u[2] = hi ? c2 : x0;  pa0u.u[3] = hi ? c3 : x1;                        \
    pa1u.u[0] = hi ? x6 : c4;  pa1u.u[1] = hi ? x7 : c5;                        \
    pa1u.u[2] = hi ? c6 : x4;  pa1u.u[3] = hi ? c7 : x5;                        \
    o0 = __builtin_amdgcn_mfma_f32_32x32x16_bf16(pa0u.v, CV[0], o0, 0, 0, 0);   \
    o0 = __builtin_amdgcn_mfma_f32_32x32x16_bf16(pa1u.v, CV[1], o0, 0, 0, 0);   \
    o1 = __builtin_amdgcn_mfma_f32_32x32x16_bf16(pa0u.v, CV[2], o1, 0, 0, 0);   \
    o1 = __builtin_amdgcn_mfma_f32_32x32x16_bf16(pa1u.v, CV[3], o1, 0, 0, 0);   \
  } while (0)

__global__ __launch_bounds__(512) void attn_kernel(
    const short* __restrict__ qb, const short* __restrict__ kb,
    const short* __restrict__ vtb, short* __restrict__ concat)
{
  const int T = 2048;
  int id = blockIdx.x;                 // 256 blocks
  int grp = id & 7;                    // XCD-ish group: bh {4*grp .. 4*grp+3}
  int p   = id >> 3;                   // q-pair 0..31
  int wid = threadIdx.x >> 6;
  int e   = wid & 3;                   // task slot (bh within group)
  int s   = wid >> 2;                  // kv parity 0/1
  int bh = grp * 4 + e;
  int lane = threadIdx.x & 63;
  int q32 = lane & 31;
  int hi  = lane >> 5;
  int h = bh & 15, b = bh >> 4;

  __shared__ float partLDS[4][16][64][2];   // [slot][r2][lane][pair] 32KB
  __shared__ float mlLDS[4][64][2];         // [slot][lane][m,l]      2KB

  const short* Q  = qb  + (size_t)bh * T * 64;
  const short* Kg = kb  + (size_t)bh * T * 64;  // [t][d]
  const short* Vt = vtb + (size_t)bh * 64 * T;  // [d][t]

  float slope2 = exp2f(-0.5f * (float)(h + 1)) * 1.44269504f;

  for (int task = 0; task < 2; ++task){
    int j = task ? (63 - p) : p;
    int q0 = j * 32;
    int qpos = q0 + q32;

    bf16x8 qf[4];
    #pragma unroll
    for (int ks = 0; ks < 4; ++ks)
      qf[ks] = *(const bf16x8*)(Q + (size_t)qpos * 64 + ks * 16 + hi * 8);

    f32x16 o0, o1;
    #pragma unroll
    for (int i = 0; i < 16; ++i){ o0[i] = 0.f; o1[i] = 0.f; }
    float m_run = -1e30f, l_run = 0.f;

    if (s <= j){
      // descending kv: start at largest tile of this parity (diagonal side)
      int t0 = j - ((j - s) & 1);
      bf16x8 kA[4], vA[4], kB[4], vB[4];
      KVLOAD(kA, vA, t0);
      int t = t0;
      while (1){
        PROC(kA, vA, t, (t - 2 >= s), kB, vB);
        t -= 2; if (t < s) break;
        PROC(kB, vB, t, (t - 2 >= s), kA, vA);
        t -= 2; if (t < s) break;
      }
    }

    if (s == 0){
      #pragma unroll
      for (int r2 = 0; r2 < 8; ++r2){
        partLDS[e][r2][lane][0]     = o0[2 * r2];
        partLDS[e][r2][lane][1]     = o0[2 * r2 + 1];
        partLDS[e][r2 + 8][lane][0] = o1[2 * r2];
        partLDS[e][r2 + 8][lane][1] = o1[2 * r2 + 1];
      }
      mlLDS[e][lane][0] = m_run;
      mlLDS[e][lane][1] = l_run;
    }
    __syncthreads();
    if (s == 1){
      float mE = mlLDS[e][lane][0];
      float lE = mlLDS[e][lane][1];
      float mS = fmaxf(mE, m_run);
      float aE = exp2f(mE - mS);
      float aO = exp2f(m_run - mS);
      float lT = aE * lE + aO * l_run;
      float linv = 1.f / lT;
      float fE = aE * linv;
      float fO = aO * linv;
      #pragma unroll
      for (int r = 0; r < 16; ++r){
        int crow = CBI(r) + 4 * hi;
        float fEr = __shfl(fE, crow, 64);
        float fOr = __shfl(fO, crow, 64);
        float oE0 = partLDS[e][r >> 1][lane][r & 1];
        float oE1 = partLDS[e][8 + (r >> 1)][lane][r & 1];
        size_t base = ((size_t)(b * 2048 + q0 + crow)) * 1024 + h * 64;
        concat[base + q32]      = f2bf(fEr * oE0 + fOr * o0[r]);
        concat[base + 32 + q32] = f2bf(fEr * oE1 + fOr * o1[r]);
      }
    }
    __syncthreads();
  }
}

extern "C" void kernel_launch(void* const* d_in, const int* in_sizes, int n_in,
                              void* d_out, int out_size, void* d_ws, size_t ws_size,
                              hipStream_t stream)
{
  (void)in_sizes; (void)n_in; (void)out_size; (void)ws_size;
  const float* x     = (const float*)d_in[0];
  const float* g1    = (const float*)d_in[1];
  const float* w_qkv = (const float*)d_in[2];
  const float* w_o   = (const float*)d_in[3];
  const float* g2    = (const float*)d_in[4];
  const float* W     = (const float*)d_in[5];
  const float* V     = (const float*)d_in[6];
  const float* W2    = (const float*)d_in[7];
  float* out = (float*)d_out;

  char* wsb = (char*)d_ws;
  size_t off = 0;
  auto alloc = [&](size_t bytes) -> void* {
    void* p = wsb + off;
    off += (bytes + 255) & ~(size_t)255;
    return p;
  };
  short* wqkvT = (short*)alloc((size_t)3072 * 1024 * 2);
  short* woT   = (short*)alloc((size_t)1024 * 1024 * 2);
  short* WT    = (short*)alloc((size_t)2816 * 1024 * 2);
  short* VT    = (short*)alloc((size_t)2816 * 1024 * 2);
  short* W2T   = (short*)alloc((size_t)1024 * 2816 * 2);
  short* h1    = (short*)alloc((size_t)4096 * 1024 * 2);
  short* qbuf  = (short*)alloc((size_t)4096 * 1024 * 2);
  short* kbuf  = (short*)alloc((size_t)4096 * 1024 * 2);
  short* vbuf  = (short*)alloc((size_t)4096 * 1024 * 2); // [B,H,T,64]
  short* vtbuf = (short*)alloc((size_t)4096 * 1024 * 2); // [B,H,64,T]
  short* conc  = (short*)alloc((size_t)4096 * 1024 * 2);
  float* x2    = (float*)alloc((size_t)4096 * 1024 * 4);
  short* h2    = (short*)alloc((size_t)4096 * 1024 * 2);
  short* gated = (short*)alloc((size_t)4096 * 2816 * 2);

  dim3 tb(32, 8);
  hipLaunchKernelGGL(transpose_bf16_kernel, dim3(96, 32), tb, 0, stream, w_qkv, wqkvT, 1024, 3072, 3072, 1024);
  hipLaunchKernelGGL(transpose_bf16_kernel, dim3(32, 32), tb, 0, stream, w_o,   woT,   1024, 1024, 1024, 1024);
  hipLaunchKernelGGL(transpose_bf16_kernel, dim3(88, 32), tb, 0, stream, W,     WT,    1024, 2728, 2816, 1024);
  hipLaunchKernelGGL(transpose_bf16_kernel, dim3(88, 32), tb, 0, stream, V,     VT,    1024, 2728, 2816, 1024);
  hipLaunchKernelGGL(transpose_bf16_kernel, dim3(32, 88), tb, 0, stream, W2,    W2T,   2728, 1024, 1024, 2816);

  hipLaunchKernelGGL(rmsnorm_kernel, dim3(4096), dim3(256), 0, stream, x, g1, h1);

  hipLaunchKernelGGL((gemm_dp_kernel<128, 128, EPI_QKV>), dim3(768), dim3(512), 0, stream,
                     h1, wqkvT, 4096, 3072, 1024,
                     (float*)nullptr, (short*)nullptr, (const float*)nullptr,
                     qbuf, kbuf, vbuf);

  hipLaunchKernelGGL(transpose_bb_kernel, dim3(64, 2, 32), tb, 0, stream, vbuf, vtbuf);

  hipLaunchKernelGGL(attn_kernel, dim3(256), dim3(512), 0, stream, qbuf, kbuf, vtbuf, conc);

  hipLaunchKernelGGL((gemm_dp_kernel<128, 128, EPI_RESID>), dim3(256), dim3(512), 0, stream,
                     conc, woT, 4096, 1024, 1024,
                     x2, (short*)nullptr, x,
                     (short*)nullptr, (short*)nullptr, (short*)nullptr);

  hipLaunchKernelGGL(rmsnorm_kernel, dim3(4096), dim3(256), 0, stream, x2, g2, h2);

  hipLaunchKernelGGL(gemm_wv_kernel, dim3(704), dim3(512), 0, stream,
                     h2, WT, VT, 4096, 2816, 1024, gated);

  hipLaunchKernelGGL((gemm_dp_kernel<128, 128, EPI_RESID>), dim3(256), dim3(512), 0, stream,
                     gated, W2T, 4096, 1024, 2816,
                     out, (short*)nullptr, x2,
                     (short*)nullptr, (short*)nullptr, (short*)nullptr);
}

// Round 19
// 259.285 us; speedup vs baseline: 1.0959x; 1.0254x over previous
//
#include <hip/hip_runtime.h>
#include <math.h>

typedef __attribute__((ext_vector_type(8))) short bf16x8;
typedef __attribute__((ext_vector_type(4))) float f32x4;
typedef __attribute__((ext_vector_type(16))) float f32x16;

static __device__ __forceinline__ short f2bf(float x){
  union { float f; unsigned u; } a; a.f = x;
  unsigned r = a.u + 0x7fffu + ((a.u >> 16) & 1u);
  return (short)(r >> 16);
}

static __device__ __forceinline__ unsigned cvtpk(float lo, float hi){
  unsigned r; asm("v_cvt_pk_bf16_f32 %0, %1, %2" : "=v"(r) : "v"(lo), "v"(hi)); return r;
}

// fused weight transposes: out[i][j] = (i<IC && j<IR) ? in[j][i] : 0 (bf16).
// Five transposes in one launch; flat block id -> (which, bx, by).
// Block counts: wqkv 96x32=3072 | wo 32x32=1024 | W 88x32=2816 | V 88x32=2816
// | W2 32x88=2816 ; offsets 0,3072,4096,6912,9728 ; total 12544.
__global__ __launch_bounds__(256) void transpose_all_kernel(
    const float* __restrict__ w_qkv, const float* __restrict__ w_o,
    const float* __restrict__ W, const float* __restrict__ V,
    const float* __restrict__ W2,
    short* __restrict__ wqkvT, short* __restrict__ woT,
    short* __restrict__ WT, short* __restrict__ VT, short* __restrict__ W2T)
{
  __shared__ float tile[32][33];
  int fid = blockIdx.x;
  const float* in; short* out; int IR, IC, OR, OC, nx, local;
  if (fid < 3072){        in = w_qkv; out = wqkvT; IR = 1024; IC = 3072; OR = 3072; OC = 1024; nx = 96; local = fid; }
  else if (fid < 4096){   in = w_o;   out = woT;   IR = 1024; IC = 1024; OR = 1024; OC = 1024; nx = 32; local = fid - 3072; }
  else if (fid < 6912){   in = W;     out = WT;    IR = 1024; IC = 2728; OR = 2816; OC = 1024; nx = 88; local = fid - 4096; }
  else if (fid < 9728){   in = V;     out = VT;    IR = 1024; IC = 2728; OR = 2816; OC = 1024; nx = 88; local = fid - 6912; }
  else {                  in = W2;    out = W2T;   IR = 2728; IC = 1024; OR = 1024; OC = 2816; nx = 32; local = fid - 9728; }
  int bx = local % nx, by = local / nx;
  int i0 = bx * 32, j0 = by * 32;
  int tx = threadIdx.x, ty = threadIdx.y;
  #pragma unroll
  for (int r = 0; r < 32; r += 8){
    int j = j0 + ty + r, i = i0 + tx;
    tile[ty + r][tx] = (j < IR && i < IC) ? in[(size_t)j * IC + i] : 0.f;
  }
  __syncthreads();
  #pragma unroll
  for (int r = 0; r < 32; r += 8){
    int oi = i0 + ty + r, oj = j0 + tx;
    if (oi < OR && oj < OC) out[(size_t)oi * OC + oj] = f2bf(tile[tx][ty + r]);
  }
}

// bf16 transpose: in [32 bh][2048][64] -> out [32 bh][64][2048]
__global__ __launch_bounds__(256) void transpose_bb_kernel(
    const short* __restrict__ in, short* __restrict__ out)
{
  __shared__ short tile[32][33];
  int bh = blockIdx.z;
  int t0 = blockIdx.x * 32;
  int d0 = blockIdx.y * 32;
  int tx = threadIdx.x, ty = threadIdx.y;
  const short* src = in + ((size_t)bh * 2048 + t0) * 64 + d0;
  #pragma unroll
  for (int r = 0; r < 32; r += 8)
    tile[ty + r][tx] = src[(size_t)(ty + r) * 64 + tx];
  __syncthreads();
  short* dst = out + ((size_t)bh * 64 + d0) * 2048 + t0;
  #pragma unroll
  for (int r = 0; r < 32; r += 8)
    dst[(size_t)(ty + r) * 2048 + tx] = tile[tx][ty + r];
}

// one block per row of 1024; h = x / (sqrt(mean(x^2)) + eps) * g  -> bf16
__global__ __launch_bounds__(256) void rmsnorm_kernel(
    const float* __restrict__ x, const float* __restrict__ g, short* __restrict__ out)
{
  int row = blockIdx.x, tid = threadIdx.x;
  const float4* xr = (const float4*)(x + (size_t)row * 1024);
  float4 v = xr[tid];
  float ss = v.x*v.x + v.y*v.y + v.z*v.z + v.w*v.w;
  #pragma unroll
  for (int m = 1; m < 64; m <<= 1) ss += __shfl_xor(ss, m, 64);
  __shared__ float sm[4];
  if ((tid & 63) == 0) sm[tid >> 6] = ss;
  __syncthreads();
  float tot = sm[0] + sm[1] + sm[2] + sm[3];
  float inv = 1.f / (sqrtf(tot * (1.f/1024.f)) + 1e-5f);
  float4 gv = ((const float4*)g)[tid];
  short4 o;
  o.x = f2bf(v.x * inv * gv.x);
  o.y = f2bf(v.y * inv * gv.y);
  o.z = f2bf(v.z * inv * gv.z);
  o.w = f2bf(v.w * inv * gv.w);
  *(short4*)(out + (size_t)row * 1024 + tid * 4) = o;
}

enum { EPI_F32 = 0, EPI_RESID = 1, EPI_QKV = 2 };

// ---------------- deep-pipeline GEMM template ------------------------------
template<int BM, int BN>
static __device__ __forceinline__ void dp_issue(
    const short* __restrict__ A, const short* __restrict__ Bt,
    short* __restrict__ lbuf, int K, int m0, int n0, int k0,
    int wave, int lane, int l)
{
  int g = (l * 8 + wave) * 64 + lane;
  const short* src;
  if (g < BM * 8){
    int row = g >> 3, cc = g & 7;
    src = A + (size_t)(m0 + row) * K + k0 + ((cc ^ (row & 7)) << 3);
  } else {
    int gb = g - BM * 8;
    int row = gb >> 3, cc = gb & 7;
    src = Bt + (size_t)(n0 + row) * K + k0 + ((cc ^ (row & 7)) << 3);
  }
  __builtin_amdgcn_global_load_lds((const __attribute__((address_space(1))) void*)src,
                                   (__attribute__((address_space(3))) void*)(lbuf + (size_t)g * 8),
                                   16, 0, 0);
}

template<int BM, int BN, int EPI>
__global__ __launch_bounds__(512, 2) void gemm_dp_kernel(
    const short* __restrict__ A, const short* __restrict__ Bt,
    int M, int N, int K,
    float* __restrict__ outF, short* __restrict__ outB,
    const float* __restrict__ resid,
    short* __restrict__ qb, short* __restrict__ kb, short* __restrict__ vb)
{
  constexpr int L  = (BM + BN) / 64;
  constexpr int WM = BM / 2, WN = BN / 4;
  constexpr int FR = WM / 16, FC = WN / 16;
  __shared__ short lds[2][(BM + BN) * 64];
  const int tid = threadIdx.x, lane = tid & 63, wave = tid >> 6;
  const int wr = wave >> 2, wc = wave & 3;
  const int la = lane & 15, lg = lane >> 4;

  int nbn = N / BN;
  int nwg = (M / BM) * nbn;
  int bid = blockIdx.x;
  int wg = ((nwg & 7) == 0) ? ((bid & 7) * (nwg >> 3) + (bid >> 3)) : bid;  // XCD swizzle
  int m0 = (wg / nbn) * BM, n0 = (wg % nbn) * BN;

  f32x4 acc[FR][FC];
  #pragma unroll
  for (int i = 0; i < FR; ++i)
    #pragma unroll
    for (int j = 0; j < FC; ++j) acc[i][j] = f32x4{0.f, 0.f, 0.f, 0.f};

  const int NT = K >> 6;

  #pragma unroll
  for (int l = 0; l < L; ++l) dp_issue<BM, BN>(A, Bt, lds[0], K, m0, n0, 0,  wave, lane, l);
  #pragma unroll
  for (int l = 0; l < L; ++l) dp_issue<BM, BN>(A, Bt, lds[1], K, m0, n0, 64, wave, lane, l);

  for (int t = 0; t < NT; ++t){
    short* curb = lds[t & 1];
    if (t + 1 < NT){
      if constexpr (L == 8)      asm volatile("s_waitcnt vmcnt(8)" ::: "memory");
      else if constexpr (L == 6) asm volatile("s_waitcnt vmcnt(6)" ::: "memory");
      else                       asm volatile("s_waitcnt vmcnt(4)" ::: "memory");
    } else {
      asm volatile("s_waitcnt vmcnt(0)" ::: "memory");
    }
    __builtin_amdgcn_s_barrier();
    __builtin_amdgcn_sched_barrier(0);

    #pragma unroll
    for (int qr = 0; qr < FR / 4; ++qr){
      #pragma unroll
      for (int qc = 0; qc < FC / 2; ++qc){
        bf16x8 af[4][2], bfv[2][2];
        #pragma unroll
        for (int ii = 0; ii < 4; ++ii){
          int r = wr * WM + (qr * 4 + ii) * 16 + la;
          #pragma unroll
          for (int ks = 0; ks < 2; ++ks)
            af[ii][ks] = *(const bf16x8*)(curb + r * 64 + (((ks * 4 + lg) ^ (r & 7)) << 3));
        }
        #pragma unroll
        for (int jc = 0; jc < 2; ++jc){
          int rb = wc * WN + (qc * 2 + jc) * 16 + la;
          #pragma unroll
          for (int ks = 0; ks < 2; ++ks)
            bfv[jc][ks] = *(const bf16x8*)(curb + BM * 64 + rb * 64 + (((ks * 4 + lg) ^ (rb & 7)) << 3));
        }
        __builtin_amdgcn_s_setprio(1);
        #pragma unroll
        for (int ii = 0; ii < 4; ++ii)
          #pragma unroll
          for (int jc = 0; jc < 2; ++jc){
            acc[qr*4+ii][qc*2+jc] = __builtin_amdgcn_mfma_f32_16x16x32_bf16(
                af[ii][0], bfv[jc][0], acc[qr*4+ii][qc*2+jc], 0, 0, 0);
            acc[qr*4+ii][qc*2+jc] = __builtin_amdgcn_mfma_f32_16x16x32_bf16(
                af[ii][1], bfv[jc][1], acc[qr*4+ii][qc*2+jc], 0, 0, 0);
          }
        __builtin_amdgcn_s_setprio(0);
      }
    }
    __builtin_amdgcn_sched_barrier(0);
    __builtin_amdgcn_s_barrier();
    __builtin_amdgcn_sched_barrier(0);
    if (t + 2 < NT){
      #pragma unroll
      for (int l = 0; l < L; ++l)
        dp_issue<BM, BN>(A, Bt, curb, K, m0, n0, (t + 2) << 6, wave, lane, l);
    }
  }

  #pragma unroll
  for (int i = 0; i < FR; ++i){
    #pragma unroll
    for (int j = 0; j < FC; ++j){
      #pragma unroll
      for (int rr = 0; rr < 4; ++rr){
        int row = m0 + wr * WM + i * 16 + lg * 4 + rr;
        int col = n0 + wc * WN + j * 16 + la;
        float v = acc[i][j][rr];
        size_t idx = (size_t)row * N + col;
        if (EPI == EPI_F32){
          outF[idx] = v;
        } else if (EPI == EPI_RESID){
          outF[idx] = v + resid[idx];
        } else { // EPI_QKV: q scaled by (1/32)*log2(e) for exp2-domain softmax
          int which = col >> 10;
          int hh = (col & 1023) >> 6;
          int d = col & 63;
          int bb = row >> 11, tt = row & 2047;
          size_t o = (((size_t)(bb * 16 + hh) * 2048) + tt) * 64 + d;
          if (which == 0)      qb[o] = f2bf(v * 0.045084220f);
          else if (which == 1) kb[o] = f2bf(v);
          else                 vb[o] = f2bf(v);
        }
      }
    }
  }
}

// ---------------- fused W&V GEMM + SwiGLU gate -----------------------------
static __device__ __forceinline__ void wv_issue(
    const short* __restrict__ A, const short* __restrict__ Bw, const short* __restrict__ Bv,
    short* __restrict__ lbuf, int K, int m0, int n0, int k0,
    int wave, int lane, int l)
{
  int g = (l * 8 + wave) * 64 + lane;     // 0..3071
  const short* src;
  if (g < 1024){
    int row = g >> 3, cc = g & 7;
    src = A + (size_t)(m0 + row) * K + k0 + ((cc ^ (row & 7)) << 3);
  } else if (g < 2048){
    int gb = g - 1024;
    int row = gb >> 3, cc = gb & 7;
    src = Bw + (size_t)(n0 + row) * K + k0 + ((cc ^ (row & 7)) << 3);
  } else {
    int gb = g - 2048;
    int row = gb >> 3, cc = gb & 7;
    src = Bv + (size_t)(n0 + row) * K + k0 + ((cc ^ (row & 7)) << 3);
  }
  __builtin_amdgcn_global_load_lds((const __attribute__((address_space(1))) void*)src,
                                   (__attribute__((address_space(3))) void*)(lbuf + (size_t)g * 8),
                                   16, 0, 0);
}

__global__ __launch_bounds__(512, 2) void gemm_wv_kernel(
    const short* __restrict__ A, const short* __restrict__ Bw, const short* __restrict__ Bv,
    int M, int N, int K, short* __restrict__ outGated)
{
  __shared__ short lds[2][384 * 64];
  const int tid = threadIdx.x, lane = tid & 63, wave = tid >> 6;
  const int wr = wave >> 2, wc = wave & 3;
  const int la = lane & 15, lg = lane >> 4;

  int nbn = N >> 7;
  int nwg = (M >> 7) * nbn;
  int bid = blockIdx.x;
  int wg = ((nwg & 7) == 0) ? ((bid & 7) * (nwg >> 3) + (bid >> 3)) : bid;
  int m0 = (wg / nbn) << 7, n0 = (wg % nbn) << 7;

  f32x4 accW[4][2], accV[4][2];
  #pragma unroll
  for (int i = 0; i < 4; ++i)
    #pragma unroll
    for (int j = 0; j < 2; ++j){
      accW[i][j] = f32x4{0.f, 0.f, 0.f, 0.f};
      accV[i][j] = f32x4{0.f, 0.f, 0.f, 0.f};
    }

  const int NT = K >> 6;

  #pragma unroll
  for (int l = 0; l < 6; ++l) wv_issue(A, Bw, Bv, lds[0], K, m0, n0, 0,  wave, lane, l);
  #pragma unroll
  for (int l = 0; l < 6; ++l) wv_issue(A, Bw, Bv, lds[1], K, m0, n0, 64, wave, lane, l);

  for (int t = 0; t < NT; ++t){
    short* curb = lds[t & 1];
    if (t + 1 < NT) asm volatile("s_waitcnt vmcnt(6)" ::: "memory");
    else            asm volatile("s_waitcnt vmcnt(0)" ::: "memory");
    __builtin_amdgcn_s_barrier();
    __builtin_amdgcn_sched_barrier(0);

    bf16x8 af[4][2], bw[2][2], bv[2][2];
    #pragma unroll
    for (int ii = 0; ii < 4; ++ii){
      int r = wr * 64 + ii * 16 + la;
      #pragma unroll
      for (int ks = 0; ks < 2; ++ks)
        af[ii][ks] = *(const bf16x8*)(curb + r * 64 + (((ks * 4 + lg) ^ (r & 7)) << 3));
    }
    #pragma unroll
    for (int jc = 0; jc < 2; ++jc){
      int rb = wc * 32 + jc * 16 + la;
      #pragma unroll
      for (int ks = 0; ks < 2; ++ks){
        bw[jc][ks] = *(const bf16x8*)(curb +  8192 + rb * 64 + (((ks * 4 + lg) ^ (rb & 7)) << 3));
        bv[jc][ks] = *(const bf16x8*)(curb + 16384 + rb * 64 + (((ks * 4 + lg) ^ (rb & 7)) << 3));
      }
    }
    __builtin_amdgcn_s_setprio(1);
    #pragma unroll
    for (int ii = 0; ii < 4; ++ii)
      #pragma unroll
      for (int jc = 0; jc < 2; ++jc){
        accW[ii][jc] = __builtin_amdgcn_mfma_f32_16x16x32_bf16(af[ii][0], bw[jc][0], accW[ii][jc], 0, 0, 0);
        accW[ii][jc] = __builtin_amdgcn_mfma_f32_16x16x32_bf16(af[ii][1], bw[jc][1], accW[ii][jc], 0, 0, 0);
        accV[ii][jc] = __builtin_amdgcn_mfma_f32_16x16x32_bf16(af[ii][0], bv[jc][0], accV[ii][jc], 0, 0, 0);
        accV[ii][jc] = __builtin_amdgcn_mfma_f32_16x16x32_bf16(af[ii][1], bv[jc][1], accV[ii][jc], 0, 0, 0);
      }
    __builtin_amdgcn_s_setprio(0);
    __builtin_amdgcn_sched_barrier(0);
    __builtin_amdgcn_s_barrier();
    __builtin_amdgcn_sched_barrier(0);
    if (t + 2 < NT){
      #pragma unroll
      for (int l = 0; l < 6; ++l)
        wv_issue(A, Bw, Bv, curb, K, m0, n0, (t + 2) << 6, wave, lane, l);
    }
  }

  #pragma unroll
  for (int i = 0; i < 4; ++i){
    #pragma unroll
    for (int j = 0; j < 2; ++j){
      #pragma unroll
      for (int rr = 0; rr < 4; ++rr){
        int row = m0 + wr * 64 + i * 16 + lg * 4 + rr;
        int col = n0 + wc * 32 + j * 16 + la;
        float gg = accW[i][j][rr];
        float vv = accV[i][j][rr];
        float s = gg / (1.f + __expf(-gg));
        outGated[(size_t)row * N + col] = f2bf(s * vv);
      }
    }
  }
}

// ---------------- flash attention: R16 structure, DIAGONAL-FIRST kv --------
// Block = 512 thr = 8 waves = 4 bh-slots x 2 kv-parities; q-pair (p, 63-p)
// -> every block exactly 65 tile-units (dispatch-order-proof balance).
// Descending kv (diagonal first) keeps defer-max (THR=8) active. Intra-block
// 2-way merge via LDS. shfl_xor softmax (proven).

#define CBASE(r) ((float)(((r) & 3) + 8 * ((r) >> 2)))
#define CBI(r)   ((((r) & 3) + 8 * ((r) >> 2)))

#define KVLOAD(KF, VF, T_)                                                      \
  do {                                                                          \
    _Pragma("unroll")                                                           \
    for (int ks = 0; ks < 4; ++ks)                                              \
      KF[ks] = *(const bf16x8*)(Kg + ((size_t)((T_) * 32 + q32)) * 64 + ks * 16 + hi * 8); \
    _Pragma("unroll")                                                           \
    for (int dk = 0; dk < 4; ++dk)                                              \
      VF[dk] = *(const bf16x8*)(Vt + ((size_t)((dk >> 1) * 32 + q32)) * 2048 + (T_) * 32 + (dk & 1) * 16 + hi * 8); \
  } while (0)

#define PROC(CK, CV, T_, DOPF, NK, NV)                                          \
  do {                                                                          \
    f32x16 sS;                                                                  \
    _Pragma("unroll") for (int i = 0; i < 16; ++i) sS[i] = 0.f;                 \
    sS = __builtin_amdgcn_mfma_f32_32x32x16_bf16(CK[0], qf[0], sS, 0, 0, 0);    \
    sS = __builtin_amdgcn_mfma_f32_32x32x16_bf16(CK[1], qf[1], sS, 0, 0, 0);    \
    sS = __builtin_amdgcn_mfma_f32_32x32x16_bf16(CK[2], qf[2], sS, 0, 0, 0);    \
    sS = __builtin_amdgcn_mfma_f32_32x32x16_bf16(CK[3], qf[3], sS, 0, 0, 0);    \
    if (DOPF) KVLOAD(NK, NV, (T_) - 2);                                         \
    float bb2 = slope2 * (float)((T_) * 32 + 4 * hi - qpos);                    \
    float sc[16];                                                               \
    _Pragma("unroll")                                                           \
    for (int r = 0; r < 16; ++r) sc[r] = (sS[r] + bb2) + slope2 * CBASE(r);     \
    if ((T_) == j){                                                             \
      _Pragma("unroll")                                                         \
      for (int r = 0; r < 16; ++r)                                              \
        sc[r] = (CBI(r) + 4 * hi <= q32) ? sc[r] : -1e30f;                      \
    }                                                                           \
    float t8[8], t4[4];                                                         \
    _Pragma("unroll") for (int i = 0; i < 8; ++i) t8[i] = fmaxf(sc[i], sc[i + 8]); \
    _Pragma("unroll") for (int i = 0; i < 4; ++i) t4[i] = fmaxf(t8[i], t8[i + 4]); \
    float mx = fmaxf(fmaxf(t4[0], t4[1]), fmaxf(t4[2], t4[3]));                 \
    mx = fmaxf(mx, __shfl_xor(mx, 32, 64));                                     \
    if (!__all(mx <= m_run + 8.f)){                                             \
      float mnew = fmaxf(m_run, mx);                                            \
      float aL = exp2f(m_run - mnew);                                           \
      l_run *= aL;                                                              \
      m_run = mnew;                                                             \
      _Pragma("unroll")                                                         \
      for (int r = 0; r < 16; ++r){                                             \
        float aq = __shfl(aL, CBI(r) + 4 * hi, 64);                             \
        o0[r] *= aq; o1[r] *= aq;                                               \
      }                                                                         \
    }                                                                           \
    float pr[16];                                                               \
    _Pragma("unroll")                                                           \
    for (int r = 0; r < 16; ++r) pr[r] = exp2f(sc[r] - m_run);                  \
    _Pragma("unroll") for (int i = 0; i < 8; ++i) t8[i] = pr[i] + pr[i + 8];    \
    _Pragma("unroll") for (int i = 0; i < 4; ++i) t4[i] = t8[i] + t8[i + 4];    \
    float ps = (t4[0] + t4[1]) + (t4[2] + t4[3]);                               \
    ps += __shfl_xor(ps, 32, 64);                                               \
    l_run += ps;                                                                \
    unsigned c0 = cvtpk(pr[0], pr[1]),   c1 = cvtpk(pr[2], pr[3]);              \
    unsigned c2 = cvtpk(pr[4], pr[5]),   c3 = cvtpk(pr[6], pr[7]);              \
    unsigned c4 = cvtpk(pr[8], pr[9]),   c5 = cvtpk(pr[10], pr[11]);            \
    unsigned c6 = cvtpk(pr[12], pr[13]), c7 = cvtpk(pr[14], pr[15]);            \
    unsigned x0 = (unsigned)__shfl_xor((int)c0, 32, 64), x1 = (unsigned)__shfl_xor((int)c1, 32, 64); \
    unsigned x2 = (unsigned)__shfl_xor((int)c2, 32, 64), x3 = (unsigned)__shfl_xor((int)c3, 32, 64); \
    unsigned x4 = (unsigned)__shfl_xor((int)c4, 32, 64), x5 = (unsigned)__shfl_xor((int)c5, 32, 64); \
    unsigned x6 = (unsigned)__shfl_xor((int)c6, 32, 64), x7 = (unsigned)__shfl_xor((int)c7, 32, 64); \
    union { unsigned u[4]; bf16x8 v; } pa0u, pa1u;                              \
    pa0u.u[0] = hi ? x2 : c0;  pa0u.u[1] = hi ? x3 : c1;                        \
    pa0u.u[2] = hi ? c2 : x0;  pa0u.u[3] = hi ? c3 : x1;                        \
    pa1u.u[0] = hi ? x6 : c4;  pa1u.u[1] = hi ? x7 : c5;                        \
    pa1u.u[2] = hi ? c6 : x4;  pa1u.u[3] = hi ? c7 : x5;                        \
    o0 = __builtin_amdgcn_mfma_f32_32x32x16_bf16(pa0u.v, CV[0], o0, 0, 0, 0);   \
    o0 = __builtin_amdgcn_mfma_f32_32x32x16_bf16(pa1u.v, CV[1], o0, 0, 0, 0);   \
    o1 = __builtin_amdgcn_mfma_f32_32x32x16_bf16(pa0u.v, CV[2], o1, 0, 0, 0);   \
    o1 = __builtin_amdgcn_mfma_f32_32x32x16_bf16(pa1u.v, CV[3], o1, 0, 0, 0);   \
  } while (0)

__global__ __launch_bounds__(512) void attn_kernel(
    const short* __restrict__ qb, const short* __restrict__ kb,
    const short* __restrict__ vtb, short* __restrict__ concat)
{
  const int T = 2048;
  int id = blockIdx.x;                 // 256 blocks
  int grp = id & 7;                    // XCD-ish group: bh {4*grp .. 4*grp+3}
  int p   = id >> 3;                   // q-pair 0..31
  int wid = threadIdx.x >> 6;
  int e   = wid & 3;                   // task slot (bh within group)
  int s   = wid >> 2;                  // kv parity 0/1
  int bh = grp * 4 + e;
  int lane = threadIdx.x & 63;
  int q32 = lane & 31;
  int hi  = lane >> 5;
  int h = bh & 15, b = bh >> 4;

  __shared__ float partLDS[4][16][64][2];   // [slot][r2][lane][pair] 32KB
  __shared__ float mlLDS[4][64][2];         // [slot][lane][m,l]      2KB

  const short* Q  = qb  + (size_t)bh * T * 64;
  const short* Kg = kb  + (size_t)bh * T * 64;  // [t][d]
  const short* Vt = vtb + (size_t)bh * 64 * T;  // [d][t]

  float slope2 = exp2f(-0.5f * (float)(h + 1)) * 1.44269504f;

  for (int task = 0; task < 2; ++task){
    int j = task ? (63 - p) : p;
    int q0 = j * 32;
    int qpos = q0 + q32;

    bf16x8 qf[4];
    #pragma unroll
    for (int ks = 0; ks < 4; ++ks)
      qf[ks] = *(const bf16x8*)(Q + (size_t)qpos * 64 + ks * 16 + hi * 8);

    f32x16 o0, o1;
    #pragma unroll
    for (int i = 0; i < 16; ++i){ o0[i] = 0.f; o1[i] = 0.f; }
    float m_run = -1e30f, l_run = 0.f;

    if (s <= j){
      // descending kv: start at largest tile of this parity (diagonal side)
      int t0 = j - ((j - s) & 1);
      bf16x8 kA[4], vA[4], kB[4], vB[4];
      KVLOAD(kA, vA, t0);
      int t = t0;
      while (1){
        PROC(kA, vA, t, (t - 2 >= s), kB, vB);
        t -= 2; if (t < s) break;
        PROC(kB, vB, t, (t - 2 >= s), kA, vA);
        t -= 2; if (t < s) break;
      }
    }

    if (s == 0){
      #pragma unroll
      for (int r2 = 0; r2 < 8; ++r2){
        partLDS[e][r2][lane][0]     = o0[2 * r2];
        partLDS[e][r2][lane][1]     = o0[2 * r2 + 1];
        partLDS[e][r2 + 8][lane][0] = o1[2 * r2];
        partLDS[e][r2 + 8][lane][1] = o1[2 * r2 + 1];
      }
      mlLDS[e][lane][0] = m_run;
      mlLDS[e][lane][1] = l_run;
    }
    __syncthreads();
    if (s == 1){
      float mE = mlLDS[e][lane][0];
      float lE = mlLDS[e][lane][1];
      float mS = fmaxf(mE, m_run);
      float aE = exp2f(mE - mS);
      float aO = exp2f(m_run - mS);
      float lT = aE * lE + aO * l_run;
      float linv = 1.f / lT;
      float fE = aE * linv;
      float fO = aO * linv;
      #pragma unroll
      for (int r = 0; r < 16; ++r){
        int crow = CBI(r) + 4 * hi;
        float fEr = __shfl(fE, crow, 64);
        float fOr = __shfl(fO, crow, 64);
        float oE0 = partLDS[e][r >> 1][lane][r & 1];
        float oE1 = partLDS[e][8 + (r >> 1)][lane][r & 1];
        size_t base = ((size_t)(b * 2048 + q0 + crow)) * 1024 + h * 64;
        concat[base + q32]      = f2bf(fEr * oE0 + fOr * o0[r]);
        concat[base + 32 + q32] = f2bf(fEr * oE1 + fOr * o1[r]);
      }
    }
    __syncthreads();
  }
}

extern "C" void kernel_launch(void* const* d_in, const int* in_sizes, int n_in,
                              void* d_out, int out_size, void* d_ws, size_t ws_size,
                              hipStream_t stream)
{
  (void)in_sizes; (void)n_in; (void)out_size; (void)ws_size;
  const float* x     = (const float*)d_in[0];
  const float* g1    = (const float*)d_in[1];
  const float* w_qkv = (const float*)d_in[2];
  const float* w_o   = (const float*)d_in[3];
  const float* g2    = (const float*)d_in[4];
  const float* W     = (const float*)d_in[5];
  const float* V     = (const float*)d_in[6];
  const float* W2    = (const float*)d_in[7];
  float* out = (float*)d_out;

  char* wsb = (char*)d_ws;
  size_t off = 0;
  auto alloc = [&](size_t bytes) -> void* {
    void* p = wsb + off;
    off += (bytes + 255) & ~(size_t)255;
    return p;
  };
  short* wqkvT = (short*)alloc((size_t)3072 * 1024 * 2);
  short* woT   = (short*)alloc((size_t)1024 * 1024 * 2);
  short* WT    = (short*)alloc((size_t)2816 * 1024 * 2);
  short* VT    = (short*)alloc((size_t)2816 * 1024 * 2);
  short* W2T   = (short*)alloc((size_t)1024 * 2816 * 2);
  short* h1    = (short*)alloc((size_t)4096 * 1024 * 2);
  short* qbuf  = (short*)alloc((size_t)4096 * 1024 * 2);
  short* kbuf  = (short*)alloc((size_t)4096 * 1024 * 2);
  short* vbuf  = (short*)alloc((size_t)4096 * 1024 * 2); // [B,H,T,64]
  short* vtbuf = (short*)alloc((size_t)4096 * 1024 * 2); // [B,H,64,T]
  short* conc  = (short*)alloc((size_t)4096 * 1024 * 2);
  float* x2    = (float*)alloc((size_t)4096 * 1024 * 4);
  short* h2    = (short*)alloc((size_t)4096 * 1024 * 2);
  short* gated = (short*)alloc((size_t)4096 * 2816 * 2);

  dim3 tb(32, 8);
  // fused weight transposes: one launch replaces five
  hipLaunchKernelGGL(transpose_all_kernel, dim3(12544), tb, 0, stream,
                     w_qkv, w_o, W, V, W2, wqkvT, woT, WT, VT, W2T);

  hipLaunchKernelGGL(rmsnorm_kernel, dim3(4096), dim3(256), 0, stream, x, g1, h1);

  hipLaunchKernelGGL((gemm_dp_kernel<128, 128, EPI_QKV>), dim3(768), dim3(512), 0, stream,
                     h1, wqkvT, 4096, 3072, 1024,
                     (float*)nullptr, (short*)nullptr, (const float*)nullptr,
                     qbuf, kbuf, vbuf);

  hipLaunchKernelGGL(transpose_bb_kernel, dim3(64, 2, 32), tb, 0, stream, vbuf, vtbuf);

  hipLaunchKernelGGL(attn_kernel, dim3(256), dim3(512), 0, stream, qbuf, kbuf, vtbuf, conc);

  hipLaunchKernelGGL((gemm_dp_kernel<128, 128, EPI_RESID>), dim3(256), dim3(512), 0, stream,
                     conc, woT, 4096, 1024, 1024,
                     x2, (short*)nullptr, x,
                     (short*)nullptr, (short*)nullptr, (short*)nullptr);

  hipLaunchKernelGGL(rmsnorm_kernel, dim3(4096), dim3(256), 0, stream, x2, g2, h2);

  hipLaunchKernelGGL(gemm_wv_kernel, dim3(704), dim3(512), 0, stream,
                     h2, WT, VT, 4096, 2816, 1024, gated);

  hipLaunchKernelGGL((gemm_dp_kernel<128, 128, EPI_RESID>), dim3(256), dim3(512), 0, stream,
                     gated, W2T, 4096, 1024, 2816,
                     out, (short*)nullptr, x2,
                     (short*)nullptr, (short*)nullptr, (short*)nullptr);
}

// Round 20
// 257.183 us; speedup vs baseline: 1.1049x; 1.0082x over previous
//
#include <hip/hip_runtime.h>
#include <math.h>

typedef __attribute__((ext_vector_type(8))) short bf16x8;
typedef __attribute__((ext_vector_type(4))) float f32x4;
typedef __attribute__((ext_vector_type(16))) float f32x16;

static __device__ __forceinline__ short f2bf(float x){
  union { float f; unsigned u; } a; a.f = x;
  unsigned r = a.u + 0x7fffu + ((a.u >> 16) & 1u);
  return (short)(r >> 16);
}

static __device__ __forceinline__ unsigned cvtpk(float lo, float hi){
  unsigned r; asm("v_cvt_pk_bf16_f32 %0, %1, %2" : "=v"(r) : "v"(lo), "v"(hi)); return r;
}

// fused prologue: five weight transposes + rmsnorm(x,g1) in ONE launch.
// Blocks 0..12543: transposes (wqkv 3072 | wo 1024 | W 2816 | V 2816 | W2 2816).
// Blocks 12544..16639: rmsnorm rows (x depends on nothing else in prologue).
__global__ __launch_bounds__(256) void prologue_kernel(
    const float* __restrict__ w_qkv, const float* __restrict__ w_o,
    const float* __restrict__ W, const float* __restrict__ V,
    const float* __restrict__ W2,
    short* __restrict__ wqkvT, short* __restrict__ woT,
    short* __restrict__ WT, short* __restrict__ VT, short* __restrict__ W2T,
    const float* __restrict__ x, const float* __restrict__ g1, short* __restrict__ h1)
{
  __shared__ float tile[32][33];
  int fid = blockIdx.x;
  if (fid >= 12544){
    // rmsnorm row (proven body; tid flattened, wave layout identical)
    int row = fid - 12544;
    int tid = threadIdx.y * 32 + threadIdx.x;
    const float4* xr = (const float4*)(x + (size_t)row * 1024);
    float4 v = xr[tid];
    float ss = v.x*v.x + v.y*v.y + v.z*v.z + v.w*v.w;
    #pragma unroll
    for (int m = 1; m < 64; m <<= 1) ss += __shfl_xor(ss, m, 64);
    float* sm = &tile[0][0];
    if ((tid & 63) == 0) sm[tid >> 6] = ss;
    __syncthreads();
    float tot = sm[0] + sm[1] + sm[2] + sm[3];
    float inv = 1.f / (sqrtf(tot * (1.f/1024.f)) + 1e-5f);
    float4 gv = ((const float4*)g1)[tid];
    short4 o;
    o.x = f2bf(v.x * inv * gv.x);
    o.y = f2bf(v.y * inv * gv.y);
    o.z = f2bf(v.z * inv * gv.z);
    o.w = f2bf(v.w * inv * gv.w);
    *(short4*)(h1 + (size_t)row * 1024 + tid * 4) = o;
    return;
  }
  const float* in; short* out; int IR, IC, OR, OC, nx, local;
  if (fid < 3072){        in = w_qkv; out = wqkvT; IR = 1024; IC = 3072; OR = 3072; OC = 1024; nx = 96; local = fid; }
  else if (fid < 4096){   in = w_o;   out = woT;   IR = 1024; IC = 1024; OR = 1024; OC = 1024; nx = 32; local = fid - 3072; }
  else if (fid < 6912){   in = W;     out = WT;    IR = 1024; IC = 2728; OR = 2816; OC = 1024; nx = 88; local = fid - 4096; }
  else if (fid < 9728){   in = V;     out = VT;    IR = 1024; IC = 2728; OR = 2816; OC = 1024; nx = 88; local = fid - 6912; }
  else {                  in = W2;    out = W2T;   IR = 2728; IC = 1024; OR = 1024; OC = 2816; nx = 32; local = fid - 9728; }
  int bx = local % nx, by = local / nx;
  int i0 = bx * 32, j0 = by * 32;
  int tx = threadIdx.x, ty = threadIdx.y;
  #pragma unroll
  for (int r = 0; r < 32; r += 8){
    int j = j0 + ty + r, i = i0 + tx;
    tile[ty + r][tx] = (j < IR && i < IC) ? in[(size_t)j * IC + i] : 0.f;
  }
  __syncthreads();
  #pragma unroll
  for (int r = 0; r < 32; r += 8){
    int oi = i0 + ty + r, oj = j0 + tx;
    if (oi < OR && oj < OC) out[(size_t)oi * OC + oj] = f2bf(tile[tx][ty + r]);
  }
}

// bf16 transpose: in [32 bh][2048][64] -> out [32 bh][64][2048]
__global__ __launch_bounds__(256) void transpose_bb_kernel(
    const short* __restrict__ in, short* __restrict__ out)
{
  __shared__ short tile[32][33];
  int bh = blockIdx.z;
  int t0 = blockIdx.x * 32;
  int d0 = blockIdx.y * 32;
  int tx = threadIdx.x, ty = threadIdx.y;
  const short* src = in + ((size_t)bh * 2048 + t0) * 64 + d0;
  #pragma unroll
  for (int r = 0; r < 32; r += 8)
    tile[ty + r][tx] = src[(size_t)(ty + r) * 64 + tx];
  __syncthreads();
  short* dst = out + ((size_t)bh * 64 + d0) * 2048 + t0;
  #pragma unroll
  for (int r = 0; r < 32; r += 8)
    dst[(size_t)(ty + r) * 2048 + tx] = tile[tx][ty + r];
}

// one block per row of 1024; h = x / (sqrt(mean(x^2)) + eps) * g  -> bf16
__global__ __launch_bounds__(256) void rmsnorm_kernel(
    const float* __restrict__ x, const float* __restrict__ g, short* __restrict__ out)
{
  int row = blockIdx.x, tid = threadIdx.x;
  const float4* xr = (const float4*)(x + (size_t)row * 1024);
  float4 v = xr[tid];
  float ss = v.x*v.x + v.y*v.y + v.z*v.z + v.w*v.w;
  #pragma unroll
  for (int m = 1; m < 64; m <<= 1) ss += __shfl_xor(ss, m, 64);
  __shared__ float sm[4];
  if ((tid & 63) == 0) sm[tid >> 6] = ss;
  __syncthreads();
  float tot = sm[0] + sm[1] + sm[2] + sm[3];
  float inv = 1.f / (sqrtf(tot * (1.f/1024.f)) + 1e-5f);
  float4 gv = ((const float4*)g)[tid];
  short4 o;
  o.x = f2bf(v.x * inv * gv.x);
  o.y = f2bf(v.y * inv * gv.y);
  o.z = f2bf(v.z * inv * gv.z);
  o.w = f2bf(v.w * inv * gv.w);
  *(short4*)(out + (size_t)row * 1024 + tid * 4) = o;
}

enum { EPI_F32 = 0, EPI_RESID = 1, EPI_QKV = 2 };

// ---------------- deep-pipeline GEMM template ------------------------------
template<int BM, int BN>
static __device__ __forceinline__ void dp_issue(
    const short* __restrict__ A, const short* __restrict__ Bt,
    short* __restrict__ lbuf, int K, int m0, int n0, int k0,
    int wave, int lane, int l)
{
  int g = (l * 8 + wave) * 64 + lane;
  const short* src;
  if (g < BM * 8){
    int row = g >> 3, cc = g & 7;
    src = A + (size_t)(m0 + row) * K + k0 + ((cc ^ (row & 7)) << 3);
  } else {
    int gb = g - BM * 8;
    int row = gb >> 3, cc = gb & 7;
    src = Bt + (size_t)(n0 + row) * K + k0 + ((cc ^ (row & 7)) << 3);
  }
  __builtin_amdgcn_global_load_lds((const __attribute__((address_space(1))) void*)src,
                                   (__attribute__((address_space(3))) void*)(lbuf + (size_t)g * 8),
                                   16, 0, 0);
}

template<int BM, int BN, int EPI>
__global__ __launch_bounds__(512, 2) void gemm_dp_kernel(
    const short* __restrict__ A, const short* __restrict__ Bt,
    int M, int N, int K,
    float* __restrict__ outF, short* __restrict__ outB,
    const float* __restrict__ resid,
    short* __restrict__ qb, short* __restrict__ kb, short* __restrict__ vb)
{
  constexpr int L  = (BM + BN) / 64;
  constexpr int WM = BM / 2, WN = BN / 4;
  constexpr int FR = WM / 16, FC = WN / 16;
  __shared__ short lds[2][(BM + BN) * 64];
  const int tid = threadIdx.x, lane = tid & 63, wave = tid >> 6;
  const int wr = wave >> 2, wc = wave & 3;
  const int la = lane & 15, lg = lane >> 4;

  int nbn = N / BN;
  int nwg = (M / BM) * nbn;
  int bid = blockIdx.x;
  int wg = ((nwg & 7) == 0) ? ((bid & 7) * (nwg >> 3) + (bid >> 3)) : bid;  // XCD swizzle
  int m0 = (wg / nbn) * BM, n0 = (wg % nbn) * BN;

  f32x4 acc[FR][FC];
  #pragma unroll
  for (int i = 0; i < FR; ++i)
    #pragma unroll
    for (int j = 0; j < FC; ++j) acc[i][j] = f32x4{0.f, 0.f, 0.f, 0.f};

  const int NT = K >> 6;

  #pragma unroll
  for (int l = 0; l < L; ++l) dp_issue<BM, BN>(A, Bt, lds[0], K, m0, n0, 0,  wave, lane, l);
  #pragma unroll
  for (int l = 0; l < L; ++l) dp_issue<BM, BN>(A, Bt, lds[1], K, m0, n0, 64, wave, lane, l);

  for (int t = 0; t < NT; ++t){
    short* curb = lds[t & 1];
    if (t + 1 < NT){
      if constexpr (L == 8)      asm volatile("s_waitcnt vmcnt(8)" ::: "memory");
      else if constexpr (L == 6) asm volatile("s_waitcnt vmcnt(6)" ::: "memory");
      else                       asm volatile("s_waitcnt vmcnt(4)" ::: "memory");
    } else {
      asm volatile("s_waitcnt vmcnt(0)" ::: "memory");
    }
    __builtin_amdgcn_s_barrier();
    __builtin_amdgcn_sched_barrier(0);

    #pragma unroll
    for (int qr = 0; qr < FR / 4; ++qr){
      #pragma unroll
      for (int qc = 0; qc < FC / 2; ++qc){
        bf16x8 af[4][2], bfv[2][2];
        #pragma unroll
        for (int ii = 0; ii < 4; ++ii){
          int r = wr * WM + (qr * 4 + ii) * 16 + la;
          #pragma unroll
          for (int ks = 0; ks < 2; ++ks)
            af[ii][ks] = *(const bf16x8*)(curb + r * 64 + (((ks * 4 + lg) ^ (r & 7)) << 3));
        }
        #pragma unroll
        for (int jc = 0; jc < 2; ++jc){
          int rb = wc * WN + (qc * 2 + jc) * 16 + la;
          #pragma unroll
          for (int ks = 0; ks < 2; ++ks)
            bfv[jc][ks] = *(const bf16x8*)(curb + BM * 64 + rb * 64 + (((ks * 4 + lg) ^ (rb & 7)) << 3));
        }
        __builtin_amdgcn_s_setprio(1);
        #pragma unroll
        for (int ii = 0; ii < 4; ++ii)
          #pragma unroll
          for (int jc = 0; jc < 2; ++jc){
            acc[qr*4+ii][qc*2+jc] = __builtin_amdgcn_mfma_f32_16x16x32_bf16(
                af[ii][0], bfv[jc][0], acc[qr*4+ii][qc*2+jc], 0, 0, 0);
            acc[qr*4+ii][qc*2+jc] = __builtin_amdgcn_mfma_f32_16x16x32_bf16(
                af[ii][1], bfv[jc][1], acc[qr*4+ii][qc*2+jc], 0, 0, 0);
          }
        __builtin_amdgcn_s_setprio(0);
      }
    }
    __builtin_amdgcn_sched_barrier(0);
    __builtin_amdgcn_s_barrier();
    __builtin_amdgcn_sched_barrier(0);
    if (t + 2 < NT){
      #pragma unroll
      for (int l = 0; l < L; ++l)
        dp_issue<BM, BN>(A, Bt, curb, K, m0, n0, (t + 2) << 6, wave, lane, l);
    }
  }

  #pragma unroll
  for (int i = 0; i < FR; ++i){
    #pragma unroll
    for (int j = 0; j < FC; ++j){
      #pragma unroll
      for (int rr = 0; rr < 4; ++rr){
        int row = m0 + wr * WM + i * 16 + lg * 4 + rr;
        int col = n0 + wc * WN + j * 16 + la;
        float v = acc[i][j][rr];
        size_t idx = (size_t)row * N + col;
        if (EPI == EPI_F32){
          outF[idx] = v;
        } else if (EPI == EPI_RESID){
          outF[idx] = v + resid[idx];
        } else { // EPI_QKV: q scaled by (1/32)*log2(e) for exp2-domain softmax
          int which = col >> 10;
          int hh = (col & 1023) >> 6;
          int d = col & 63;
          int bb = row >> 11, tt = row & 2047;
          size_t o = (((size_t)(bb * 16 + hh) * 2048) + tt) * 64 + d;
          if (which == 0)      qb[o] = f2bf(v * 0.045084220f);
          else if (which == 1) kb[o] = f2bf(v);
          else                 vb[o] = f2bf(v);
        }
      }
    }
  }
}

// ---------------- fused W&V GEMM + SwiGLU gate -----------------------------
static __device__ __forceinline__ void wv_issue(
    const short* __restrict__ A, const short* __restrict__ Bw, const short* __restrict__ Bv,
    short* __restrict__ lbuf, int K, int m0, int n0, int k0,
    int wave, int lane, int l)
{
  int g = (l * 8 + wave) * 64 + lane;     // 0..3071
  const short* src;
  if (g < 1024){
    int row = g >> 3, cc = g & 7;
    src = A + (size_t)(m0 + row) * K + k0 + ((cc ^ (row & 7)) << 3);
  } else if (g < 2048){
    int gb = g - 1024;
    int row = gb >> 3, cc = gb & 7;
    src = Bw + (size_t)(n0 + row) * K + k0 + ((cc ^ (row & 7)) << 3);
  } else {
    int gb = g - 2048;
    int row = gb >> 3, cc = gb & 7;
    src = Bv + (size_t)(n0 + row) * K + k0 + ((cc ^ (row & 7)) << 3);
  }
  __builtin_amdgcn_global_load_lds((const __attribute__((address_space(1))) void*)src,
                                   (__attribute__((address_space(3))) void*)(lbuf + (size_t)g * 8),
                                   16, 0, 0);
}

__global__ __launch_bounds__(512, 2) void gemm_wv_kernel(
    const short* __restrict__ A, const short* __restrict__ Bw, const short* __restrict__ Bv,
    int M, int N, int K, short* __restrict__ outGated)
{
  __shared__ short lds[2][384 * 64];
  const int tid = threadIdx.x, lane = tid & 63, wave = tid >> 6;
  const int wr = wave >> 2, wc = wave & 3;
  const int la = lane & 15, lg = lane >> 4;

  int nbn = N >> 7;
  int nwg = (M >> 7) * nbn;
  int bid = blockIdx.x;
  int wg = ((nwg & 7) == 0) ? ((bid & 7) * (nwg >> 3) + (bid >> 3)) : bid;
  int m0 = (wg / nbn) << 7, n0 = (wg % nbn) << 7;

  f32x4 accW[4][2], accV[4][2];
  #pragma unroll
  for (int i = 0; i < 4; ++i)
    #pragma unroll
    for (int j = 0; j < 2; ++j){
      accW[i][j] = f32x4{0.f, 0.f, 0.f, 0.f};
      accV[i][j] = f32x4{0.f, 0.f, 0.f, 0.f};
    }

  const int NT = K >> 6;

  #pragma unroll
  for (int l = 0; l < 6; ++l) wv_issue(A, Bw, Bv, lds[0], K, m0, n0, 0,  wave, lane, l);
  #pragma unroll
  for (int l = 0; l < 6; ++l) wv_issue(A, Bw, Bv, lds[1], K, m0, n0, 64, wave, lane, l);

  for (int t = 0; t < NT; ++t){
    short* curb = lds[t & 1];
    if (t + 1 < NT) asm volatile("s_waitcnt vmcnt(6)" ::: "memory");
    else            asm volatile("s_waitcnt vmcnt(0)" ::: "memory");
    __builtin_amdgcn_s_barrier();
    __builtin_amdgcn_sched_barrier(0);

    bf16x8 af[4][2], bw[2][2], bv[2][2];
    #pragma unroll
    for (int ii = 0; ii < 4; ++ii){
      int r = wr * 64 + ii * 16 + la;
      #pragma unroll
      for (int ks = 0; ks < 2; ++ks)
        af[ii][ks] = *(const bf16x8*)(curb + r * 64 + (((ks * 4 + lg) ^ (r & 7)) << 3));
    }
    #pragma unroll
    for (int jc = 0; jc < 2; ++jc){
      int rb = wc * 32 + jc * 16 + la;
      #pragma unroll
      for (int ks = 0; ks < 2; ++ks){
        bw[jc][ks] = *(const bf16x8*)(curb +  8192 + rb * 64 + (((ks * 4 + lg) ^ (rb & 7)) << 3));
        bv[jc][ks] = *(const bf16x8*)(curb + 16384 + rb * 64 + (((ks * 4 + lg) ^ (rb & 7)) << 3));
      }
    }
    __builtin_amdgcn_s_setprio(1);
    #pragma unroll
    for (int ii = 0; ii < 4; ++ii)
      #pragma unroll
      for (int jc = 0; jc < 2; ++jc){
        accW[ii][jc] = __builtin_amdgcn_mfma_f32_16x16x32_bf16(af[ii][0], bw[jc][0], accW[ii][jc], 0, 0, 0);
        accW[ii][jc] = __builtin_amdgcn_mfma_f32_16x16x32_bf16(af[ii][1], bw[jc][1], accW[ii][jc], 0, 0, 0);
        accV[ii][jc] = __builtin_amdgcn_mfma_f32_16x16x32_bf16(af[ii][0], bv[jc][0], accV[ii][jc], 0, 0, 0);
        accV[ii][jc] = __builtin_amdgcn_mfma_f32_16x16x32_bf16(af[ii][1], bv[jc][1], accV[ii][jc], 0, 0, 0);
      }
    __builtin_amdgcn_s_setprio(0);
    __builtin_amdgcn_sched_barrier(0);
    __builtin_amdgcn_s_barrier();
    __builtin_amdgcn_sched_barrier(0);
    if (t + 2 < NT){
      #pragma unroll
      for (int l = 0; l < 6; ++l)
        wv_issue(A, Bw, Bv, curb, K, m0, n0, (t + 2) << 6, wave, lane, l);
    }
  }

  #pragma unroll
  for (int i = 0; i < 4; ++i){
    #pragma unroll
    for (int j = 0; j < 2; ++j){
      #pragma unroll
      for (int rr = 0; rr < 4; ++rr){
        int row = m0 + wr * 64 + i * 16 + lg * 4 + rr;
        int col = n0 + wc * 32 + j * 16 + la;
        float gg = accW[i][j][rr];
        float vv = accV[i][j][rr];
        float s = gg / (1.f + __expf(-gg));
        outGated[(size_t)row * N + col] = f2bf(s * vv);
      }
    }
  }
}

// ---------------- flash attention: R16 structure, DIAGONAL-FIRST kv --------
// Block = 512 thr = 8 waves = 4 bh-slots x 2 kv-parities; q-pair (p, 63-p)
// -> every block exactly 65 tile-units (dispatch-order-proof balance).
// Descending kv (diagonal first) keeps defer-max (THR=8) active. Intra-block
// 2-way merge via LDS. shfl_xor softmax (proven).

#define CBASE(r) ((float)(((r) & 3) + 8 * ((r) >> 2)))
#define CBI(r)   ((((r) & 3) + 8 * ((r) >> 2)))

#define KVLOAD(KF, VF, T_)                                                      \
  do {                                                                          \
    _Pragma("unroll")                                                           \
    for (int ks = 0; ks < 4; ++ks)                                              \
      KF[ks] = *(const bf16x8*)(Kg + ((size_t)((T_) * 32 + q32)) * 64 + ks * 16 + hi * 8); \
    _Pragma("unroll")                                                           \
    for (int dk = 0; dk < 4; ++dk)                                              \
      VF[dk] = *(const bf16x8*)(Vt + ((size_t)((dk >> 1) * 32 + q32)) * 2048 + (T_) * 32 + (dk & 1) * 16 + hi * 8); \
  } while (0)

#define PROC(CK, CV, T_, DOPF, NK, NV)                                          \
  do {                                                                          \
    f32x16 sS;                                                                  \
    _Pragma("unroll") for (int i = 0; i < 16; ++i) sS[i] = 0.f;                 \
    sS = __builtin_amdgcn_mfma_f32_32x32x16_bf16(CK[0], qf[0], sS, 0, 0, 0);    \
    sS = __builtin_amdgcn_mfma_f32_32x32x16_bf16(CK[1], qf[1], sS, 0, 0, 0);    \
    sS = __builtin_amdgcn_mfma_f32_32x32x16_bf16(CK[2], qf[2], sS, 0, 0, 0);    \
    sS = __builtin_amdgcn_mfma_f32_32x32x16_bf16(CK[3], qf[3], sS, 0, 0, 0);    \
    if (DOPF) KVLOAD(NK, NV, (T_) - 2);                                         \
    float bb2 = slope2 * (float)((T_) * 32 + 4 * hi - qpos);                    \
    float sc[16];                                                               \
    _Pragma("unroll")                                                           \
    for (int r = 0; r < 16; ++r) sc[r] = (sS[r] + bb2) + slope2 * CBASE(r);     \
    if ((T_) == j){                                                             \
      _Pragma("unroll")                                                         \
      for (int r = 0; r < 16; ++r)                                              \
        sc[r] = (CBI(r) + 4 * hi <= q32) ? sc[r] : -1e30f;                      \
    }                                                                           \
    float t8[8], t4[4];                                                         \
    _Pragma("unroll") for (int i = 0; i < 8; ++i) t8[i] = fmaxf(sc[i], sc[i + 8]); \
    _Pragma("unroll") for (int i = 0; i < 4; ++i) t4[i] = fmaxf(t8[i], t8[i + 4]); \
    float mx = fmaxf(fmaxf(t4[0], t4[1]), fmaxf(t4[2], t4[3]));                 \
    mx = fmaxf(mx, __shfl_xor(mx, 32, 64));                                     \
    if (!__all(mx <= m_run + 8.f)){                                             \
      float mnew = fmaxf(m_run, mx);                                            \
      float aL = exp2f(m_run - mnew);                                           \
      l_run *= aL;                                                              \
      m_run = mnew;                                                             \
      _Pragma("unroll")                                                         \
      for (int r = 0; r < 16; ++r){                                             \
        float aq = __shfl(aL, CBI(r) + 4 * hi, 64);                             \
        o0[r] *= aq; o1[r] *= aq;                                               \
      }                                                                         \
    }                                                                           \
    float pr[16];                                                               \
    _Pragma("unroll")                                                           \
    for (int r = 0; r < 16; ++r) pr[r] = exp2f(sc[r] - m_run);                  \
    _Pragma("unroll") for (int i = 0; i < 8; ++i) t8[i] = pr[i] + pr[i + 8];    \
    _Pragma("unroll") for (int i = 0; i < 4; ++i) t4[i] = t8[i] + t8[i + 4];    \
    float ps = (t4[0] + t4[1]) + (t4[2] + t4[3]);                               \
    ps += __shfl_xor(ps, 32, 64);                                               \
    l_run += ps;                                                                \
    unsigned c0 = cvtpk(pr[0], pr[1]),   c1 = cvtpk(pr[2], pr[3]);              \
    unsigned c2 = cvtpk(pr[4], pr[5]),   c3 = cvtpk(pr[6], pr[7]);              \
    unsigned c4 = cvtpk(pr[8], pr[9]),   c5 = cvtpk(pr[10], pr[11]);            \
    unsigned c6 = cvtpk(pr[12], pr[13]), c7 = cvtpk(pr[14], pr[15]);            \
    unsigned x0 = (unsigned)__shfl_xor((int)c0, 32, 64), x1 = (unsigned)__shfl_xor((int)c1, 32, 64); \
    unsigned x2 = (unsigned)__shfl_xor((int)c2, 32, 64), x3 = (unsigned)__shfl_xor((int)c3, 32, 64); \
    unsigned x4 = (unsigned)__shfl_xor((int)c4, 32, 64), x5 = (unsigned)__shfl_xor((int)c5, 32, 64); \
    unsigned x6 = (unsigned)__shfl_xor((int)c6, 32, 64), x7 = (unsigned)__shfl_xor((int)c7, 32, 64); \
    union { unsigned u[4]; bf16x8 v; } pa0u, pa1u;                              \
    pa0u.u[0] = hi ? x2 : c0;  pa0u.u[1] = hi ? x3 : c1;                        \
    pa0u.u[2] = hi ? c2 : x0;  pa0u.u[3] = hi ? c3 : x1;                        \
    pa1u.u[0] = hi ? x6 : c4;  pa1u.u[1] = hi ? x7 : c5;                        \
    pa1u.u[2] = hi ? c6 : x4;  pa1u.u[3] = hi ? c7 : x5;                        \
    o0 = __builtin_amdgcn_mfma_f32_32x32x16_bf16(pa0u.v, CV[0], o0, 0, 0, 0);   \
    o0 = __builtin_amdgcn_mfma_f32_32x32x16_bf16(pa1u.v, CV[1], o0, 0, 0, 0);   \
    o1 = __builtin_amdgcn_mfma_f32_32x32x16_bf16(pa0u.v, CV[2], o1, 0, 0, 0);   \
    o1 = __builtin_amdgcn_mfma_f32_32x32x16_bf16(pa1u.v, CV[3], o1, 0, 0, 0);   \
  } while (0)

__global__ __launch_bounds__(512) void attn_kernel(
    const short* __restrict__ qb, const short* __restrict__ kb,
    const short* __restrict__ vtb, short* __restrict__ concat)
{
  const int T = 2048;
  int id = blockIdx.x;                 // 256 blocks
  int grp = id & 7;                    // XCD-ish group: bh {4*grp .. 4*grp+3}
  int p   = id >> 3;                   // q-pair 0..31
  int wid = threadIdx.x >> 6;
  int e   = wid & 3;                   // task slot (bh within group)
  int s   = wid >> 2;                  // kv parity 0/1
  int bh = grp * 4 + e;
  int lane = threadIdx.x & 63;
  int q32 = lane & 31;
  int hi  = lane >> 5;
  int h = bh & 15, b = bh >> 4;

  __shared__ float partLDS[4][16][64][2];   // [slot][r2][lane][pair] 32KB
  __shared__ float mlLDS[4][64][2];         // [slot][lane][m,l]      2KB

  const short* Q  = qb  + (size_t)bh * T * 64;
  const short* Kg = kb  + (size_t)bh * T * 64;  // [t][d]
  const short* Vt = vtb + (size_t)bh * 64 * T;  // [d][t]

  float slope2 = exp2f(-0.5f * (float)(h + 1)) * 1.44269504f;

  for (int task = 0; task < 2; ++task){
    int j = task ? (63 - p) : p;
    int q0 = j * 32;
    int qpos = q0 + q32;

    bf16x8 qf[4];
    #pragma unroll
    for (int ks = 0; ks < 4; ++ks)
      qf[ks] = *(const bf16x8*)(Q + (size_t)qpos * 64 + ks * 16 + hi * 8);

    f32x16 o0, o1;
    #pragma unroll
    for (int i = 0; i < 16; ++i){ o0[i] = 0.f; o1[i] = 0.f; }
    float m_run = -1e30f, l_run = 0.f;

    if (s <= j){
      // descending kv: start at largest tile of this parity (diagonal side)
      int t0 = j - ((j - s) & 1);
      bf16x8 kA[4], vA[4], kB[4], vB[4];
      KVLOAD(kA, vA, t0);
      int t = t0;
      while (1){
        PROC(kA, vA, t, (t - 2 >= s), kB, vB);
        t -= 2; if (t < s) break;
        PROC(kB, vB, t, (t - 2 >= s), kA, vA);
        t -= 2; if (t < s) break;
      }
    }

    if (s == 0){
      #pragma unroll
      for (int r2 = 0; r2 < 8; ++r2){
        partLDS[e][r2][lane][0]     = o0[2 * r2];
        partLDS[e][r2][lane][1]     = o0[2 * r2 + 1];
        partLDS[e][r2 + 8][lane][0] = o1[2 * r2];
        partLDS[e][r2 + 8][lane][1] = o1[2 * r2 + 1];
      }
      mlLDS[e][lane][0] = m_run;
      mlLDS[e][lane][1] = l_run;
    }
    __syncthreads();
    if (s == 1){
      float mE = mlLDS[e][lane][0];
      float lE = mlLDS[e][lane][1];
      float mS = fmaxf(mE, m_run);
      float aE = exp2f(mE - mS);
      float aO = exp2f(m_run - mS);
      float lT = aE * lE + aO * l_run;
      float linv = 1.f / lT;
      float fE = aE * linv;
      float fO = aO * linv;
      #pragma unroll
      for (int r = 0; r < 16; ++r){
        int crow = CBI(r) + 4 * hi;
        float fEr = __shfl(fE, crow, 64);
        float fOr = __shfl(fO, crow, 64);
        float oE0 = partLDS[e][r >> 1][lane][r & 1];
        float oE1 = partLDS[e][8 + (r >> 1)][lane][r & 1];
        size_t base = ((size_t)(b * 2048 + q0 + crow)) * 1024 + h * 64;
        concat[base + q32]      = f2bf(fEr * oE0 + fOr * o0[r]);
        concat[base + 32 + q32] = f2bf(fEr * oE1 + fOr * o1[r]);
      }
    }
    __syncthreads();
  }
}

extern "C" void kernel_launch(void* const* d_in, const int* in_sizes, int n_in,
                              void* d_out, int out_size, void* d_ws, size_t ws_size,
                              hipStream_t stream)
{
  (void)in_sizes; (void)n_in; (void)out_size; (void)ws_size;
  const float* x     = (const float*)d_in[0];
  const float* g1    = (const float*)d_in[1];
  const float* w_qkv = (const float*)d_in[2];
  const float* w_o   = (const float*)d_in[3];
  const float* g2    = (const float*)d_in[4];
  const float* W     = (const float*)d_in[5];
  const float* V     = (const float*)d_in[6];
  const float* W2    = (const float*)d_in[7];
  float* out = (float*)d_out;

  char* wsb = (char*)d_ws;
  size_t off = 0;
  auto alloc = [&](size_t bytes) -> void* {
    void* p = wsb + off;
    off += (bytes + 255) & ~(size_t)255;
    return p;
  };
  short* wqkvT = (short*)alloc((size_t)3072 * 1024 * 2);
  short* woT   = (short*)alloc((size_t)1024 * 1024 * 2);
  short* WT    = (short*)alloc((size_t)2816 * 1024 * 2);
  short* VT    = (short*)alloc((size_t)2816 * 1024 * 2);
  short* W2T   = (short*)alloc((size_t)1024 * 2816 * 2);
  short* h1    = (short*)alloc((size_t)4096 * 1024 * 2);
  short* qbuf  = (short*)alloc((size_t)4096 * 1024 * 2);
  short* kbuf  = (short*)alloc((size_t)4096 * 1024 * 2);
  short* vbuf  = (short*)alloc((size_t)4096 * 1024 * 2); // [B,H,T,64]
  short* vtbuf = (short*)alloc((size_t)4096 * 1024 * 2); // [B,H,64,T]
  short* conc  = (short*)alloc((size_t)4096 * 1024 * 2);
  float* x2    = (float*)alloc((size_t)4096 * 1024 * 4);
  short* h2    = (short*)alloc((size_t)4096 * 1024 * 2);
  short* gated = (short*)alloc((size_t)4096 * 2816 * 2);

  dim3 tb(32, 8);
  // fused prologue: five weight transposes + rmsnorm1 in one launch
  hipLaunchKernelGGL(prologue_kernel, dim3(16640), tb, 0, stream,
                     w_qkv, w_o, W, V, W2, wqkvT, woT, WT, VT, W2T,
                     x, g1, h1);

  hipLaunchKernelGGL((gemm_dp_kernel<128, 128, EPI_QKV>), dim3(768), dim3(512), 0, stream,
                     h1, wqkvT, 4096, 3072, 1024,
                     (float*)nullptr, (short*)nullptr, (const float*)nullptr,
                     qbuf, kbuf, vbuf);

  hipLaunchKernelGGL(transpose_bb_kernel, dim3(64, 2, 32), tb, 0, stream, vbuf, vtbuf);

  hipLaunchKernelGGL(attn_kernel, dim3(256), dim3(512), 0, stream, qbuf, kbuf, vtbuf, conc);

  hipLaunchKernelGGL((gemm_dp_kernel<128, 128, EPI_RESID>), dim3(256), dim3(512), 0, stream,
                     conc, woT, 4096, 1024, 1024,
                     x2, (short*)nullptr, x,
                     (short*)nullptr, (short*)nullptr, (short*)nullptr);

  hipLaunchKernelGGL(rmsnorm_kernel, dim3(4096), dim3(256), 0, stream, x2, g2, h2);

  hipLaunchKernelGGL(gemm_wv_kernel, dim3(704), dim3(512), 0, stream,
                     h2, WT, VT, 4096, 2816, 1024, gated);

  hipLaunchKernelGGL((gemm_dp_kernel<128, 128, EPI_RESID>), dim3(256), dim3(512), 0, stream,
                     gated, W2T, 4096, 1024, 2816,
                     out, (short*)nullptr, x2,
                     (short*)nullptr, (short*)nullptr, (short*)nullptr);
}

// Round 22
// 256.639 us; speedup vs baseline: 1.1072x; 1.0021x over previous
//
#include <hip/hip_runtime.h>
#include <math.h>

typedef __attribute__((ext_vector_type(8))) short bf16x8;
typedef __attribute__((ext_vector_type(4))) float f32x4;
typedef __attribute__((ext_vector_type(16))) float f32x16;

static __device__ __forceinline__ short f2bf(float x){
  union { float f; unsigned u; } a; a.f = x;
  unsigned r = a.u + 0x7fffu + ((a.u >> 16) & 1u);
  return (short)(r >> 16);
}

static __device__ __forceinline__ unsigned cvtpk(float lo, float hi){
  unsigned r; asm("v_cvt_pk_bf16_f32 %0, %1, %2" : "=v"(r) : "v"(lo), "v"(hi)); return r;
}

// fused prologue: five weight transposes + rmsnorm(x,g1) in ONE launch.
// Blocks 0..12543: transposes (wqkv 3072 | wo 1024 | W 2816 | V 2816 | W2 2816).
// Blocks 12544..16639: rmsnorm rows (x depends on nothing else in prologue).
__global__ __launch_bounds__(256) void prologue_kernel(
    const float* __restrict__ w_qkv, const float* __restrict__ w_o,
    const float* __restrict__ W, const float* __restrict__ V,
    const float* __restrict__ W2,
    short* __restrict__ wqkvT, short* __restrict__ woT,
    short* __restrict__ WT, short* __restrict__ VT, short* __restrict__ W2T,
    const float* __restrict__ x, const float* __restrict__ g1, short* __restrict__ h1)
{
  __shared__ float tile[32][33];
  int fid = blockIdx.x;
  if (fid >= 12544){
    // rmsnorm row (proven body; tid flattened, wave layout identical)
    int row = fid - 12544;
    int tid = threadIdx.y * 32 + threadIdx.x;
    const float4* xr = (const float4*)(x + (size_t)row * 1024);
    float4 v = xr[tid];
    float ss = v.x*v.x + v.y*v.y + v.z*v.z + v.w*v.w;
    #pragma unroll
    for (int m = 1; m < 64; m <<= 1) ss += __shfl_xor(ss, m, 64);
    float* sm = &tile[0][0];
    if ((tid & 63) == 0) sm[tid >> 6] = ss;
    __syncthreads();
    float tot = sm[0] + sm[1] + sm[2] + sm[3];
    float inv = 1.f / (sqrtf(tot * (1.f/1024.f)) + 1e-5f);
    float4 gv = ((const float4*)g1)[tid];
    short4 o;
    o.x = f2bf(v.x * inv * gv.x);
    o.y = f2bf(v.y * inv * gv.y);
    o.z = f2bf(v.z * inv * gv.z);
    o.w = f2bf(v.w * inv * gv.w);
    *(short4*)(h1 + (size_t)row * 1024 + tid * 4) = o;
    return;
  }
  const float* in; short* out; int IR, IC, OR, OC, nx, local;
  if (fid < 3072){        in = w_qkv; out = wqkvT; IR = 1024; IC = 3072; OR = 3072; OC = 1024; nx = 96; local = fid; }
  else if (fid < 4096){   in = w_o;   out = woT;   IR = 1024; IC = 1024; OR = 1024; OC = 1024; nx = 32; local = fid - 3072; }
  else if (fid < 6912){   in = W;     out = WT;    IR = 1024; IC = 2728; OR = 2816; OC = 1024; nx = 88; local = fid - 4096; }
  else if (fid < 9728){   in = V;     out = VT;    IR = 1024; IC = 2728; OR = 2816; OC = 1024; nx = 88; local = fid - 6912; }
  else {                  in = W2;    out = W2T;   IR = 2728; IC = 1024; OR = 1024; OC = 2816; nx = 32; local = fid - 9728; }
  int bx = local % nx, by = local / nx;
  int i0 = bx * 32, j0 = by * 32;
  int tx = threadIdx.x, ty = threadIdx.y;
  #pragma unroll
  for (int r = 0; r < 32; r += 8){
    int j = j0 + ty + r, i = i0 + tx;
    tile[ty + r][tx] = (j < IR && i < IC) ? in[(size_t)j * IC + i] : 0.f;
  }
  __syncthreads();
  #pragma unroll
  for (int r = 0; r < 32; r += 8){
    int oi = i0 + ty + r, oj = j0 + tx;
    if (oi < OR && oj < OC) out[(size_t)oi * OC + oj] = f2bf(tile[tx][ty + r]);
  }
}

// bf16 transpose: in [32 bh][2048][64] -> out [32 bh][64][2048]
__global__ __launch_bounds__(256) void transpose_bb_kernel(
    const short* __restrict__ in, short* __restrict__ out)
{
  __shared__ short tile[32][33];
  int bh = blockIdx.z;
  int t0 = blockIdx.x * 32;
  int d0 = blockIdx.y * 32;
  int tx = threadIdx.x, ty = threadIdx.y;
  const short* src = in + ((size_t)bh * 2048 + t0) * 64 + d0;
  #pragma unroll
  for (int r = 0; r < 32; r += 8)
    tile[ty + r][tx] = src[(size_t)(ty + r) * 64 + tx];
  __syncthreads();
  short* dst = out + ((size_t)bh * 64 + d0) * 2048 + t0;
  #pragma unroll
  for (int r = 0; r < 32; r += 8)
    dst[(size_t)(ty + r) * 2048 + tx] = tile[tx][ty + r];
}

// one block per row of 1024; h = x / (sqrt(mean(x^2)) + eps) * g  -> bf16
__global__ __launch_bounds__(256) void rmsnorm_kernel(
    const float* __restrict__ x, const float* __restrict__ g, short* __restrict__ out)
{
  int row = blockIdx.x, tid = threadIdx.x;
  const float4* xr = (const float4*)(x + (size_t)row * 1024);
  float4 v = xr[tid];
  float ss = v.x*v.x + v.y*v.y + v.z*v.z + v.w*v.w;
  #pragma unroll
  for (int m = 1; m < 64; m <<= 1) ss += __shfl_xor(ss, m, 64);
  __shared__ float sm[4];
  if ((tid & 63) == 0) sm[tid >> 6] = ss;
  __syncthreads();
  float tot = sm[0] + sm[1] + sm[2] + sm[3];
  float inv = 1.f / (sqrtf(tot * (1.f/1024.f)) + 1e-5f);
  float4 gv = ((const float4*)g)[tid];
  short4 o;
  o.x = f2bf(v.x * inv * gv.x);
  o.y = f2bf(v.y * inv * gv.y);
  o.z = f2bf(v.z * inv * gv.z);
  o.w = f2bf(v.w * inv * gv.w);
  *(short4*)(out + (size_t)row * 1024 + tid * 4) = o;
}

enum { EPI_F32 = 0, EPI_RESID = 1, EPI_QKV = 2 };

// ---------------- deep-pipeline GEMM template ------------------------------
template<int BM, int BN>
static __device__ __forceinline__ void dp_issue(
    const short* __restrict__ A, const short* __restrict__ Bt,
    short* __restrict__ lbuf, int K, int m0, int n0, int k0,
    int wave, int lane, int l)
{
  int g = (l * 8 + wave) * 64 + lane;
  const short* src;
  if (g < BM * 8){
    int row = g >> 3, cc = g & 7;
    src = A + (size_t)(m0 + row) * K + k0 + ((cc ^ (row & 7)) << 3);
  } else {
    int gb = g - BM * 8;
    int row = gb >> 3, cc = gb & 7;
    src = Bt + (size_t)(n0 + row) * K + k0 + ((cc ^ (row & 7)) << 3);
  }
  __builtin_amdgcn_global_load_lds((const __attribute__((address_space(1))) void*)src,
                                   (__attribute__((address_space(3))) void*)(lbuf + (size_t)g * 8),
                                   16, 0, 0);
}

template<int BM, int BN, int EPI>
__global__ __launch_bounds__(512, 2) void gemm_dp_kernel(
    const short* __restrict__ A, const short* __restrict__ Bt,
    int M, int N, int K,
    float* __restrict__ outF, short* __restrict__ outB,
    const float* __restrict__ resid,
    short* __restrict__ qb, short* __restrict__ kb, short* __restrict__ vb)
{
  constexpr int L  = (BM + BN) / 64;
  constexpr int WM = BM / 2, WN = BN / 4;
  constexpr int FR = WM / 16, FC = WN / 16;
  __shared__ short lds[2][(BM + BN) * 64];
  const int tid = threadIdx.x, lane = tid & 63, wave = tid >> 6;
  const int wr = wave >> 2, wc = wave & 3;
  const int la = lane & 15, lg = lane >> 4;

  int nbn = N / BN;
  int nwg = (M / BM) * nbn;
  int bid = blockIdx.x;
  int wg = ((nwg & 7) == 0) ? ((bid & 7) * (nwg >> 3) + (bid >> 3)) : bid;  // XCD swizzle
  int m0 = (wg / nbn) * BM, n0 = (wg % nbn) * BN;

  f32x4 acc[FR][FC];
  #pragma unroll
  for (int i = 0; i < FR; ++i)
    #pragma unroll
    for (int j = 0; j < FC; ++j) acc[i][j] = f32x4{0.f, 0.f, 0.f, 0.f};

  const int NT = K >> 6;

  #pragma unroll
  for (int l = 0; l < L; ++l) dp_issue<BM, BN>(A, Bt, lds[0], K, m0, n0, 0,  wave, lane, l);
  #pragma unroll
  for (int l = 0; l < L; ++l) dp_issue<BM, BN>(A, Bt, lds[1], K, m0, n0, 64, wave, lane, l);

  for (int t = 0; t < NT; ++t){
    short* curb = lds[t & 1];
    if (t + 1 < NT){
      if constexpr (L == 8)      asm volatile("s_waitcnt vmcnt(8)" ::: "memory");
      else if constexpr (L == 6) asm volatile("s_waitcnt vmcnt(6)" ::: "memory");
      else                       asm volatile("s_waitcnt vmcnt(4)" ::: "memory");
    } else {
      asm volatile("s_waitcnt vmcnt(0)" ::: "memory");
    }
    __builtin_amdgcn_s_barrier();
    __builtin_amdgcn_sched_barrier(0);

    #pragma unroll
    for (int qr = 0; qr < FR / 4; ++qr){
      #pragma unroll
      for (int qc = 0; qc < FC / 2; ++qc){
        bf16x8 af[4][2], bfv[2][2];
        #pragma unroll
        for (int ii = 0; ii < 4; ++ii){
          int r = wr * WM + (qr * 4 + ii) * 16 + la;
          #pragma unroll
          for (int ks = 0; ks < 2; ++ks)
            af[ii][ks] = *(const bf16x8*)(curb + r * 64 + (((ks * 4 + lg) ^ (r & 7)) << 3));
        }
        #pragma unroll
        for (int jc = 0; jc < 2; ++jc){
          int rb = wc * WN + (qc * 2 + jc) * 16 + la;
          #pragma unroll
          for (int ks = 0; ks < 2; ++ks)
            bfv[jc][ks] = *(const bf16x8*)(curb + BM * 64 + rb * 64 + (((ks * 4 + lg) ^ (rb & 7)) << 3));
        }
        __builtin_amdgcn_s_setprio(1);
        #pragma unroll
        for (int ii = 0; ii < 4; ++ii)
          #pragma unroll
          for (int jc = 0; jc < 2; ++jc){
            acc[qr*4+ii][qc*2+jc] = __builtin_amdgcn_mfma_f32_16x16x32_bf16(
                af[ii][0], bfv[jc][0], acc[qr*4+ii][qc*2+jc], 0, 0, 0);
            acc[qr*4+ii][qc*2+jc] = __builtin_amdgcn_mfma_f32_16x16x32_bf16(
                af[ii][1], bfv[jc][1], acc[qr*4+ii][qc*2+jc], 0, 0, 0);
          }
        __builtin_amdgcn_s_setprio(0);
      }
    }
    __builtin_amdgcn_sched_barrier(0);
    __builtin_amdgcn_s_barrier();
    __builtin_amdgcn_sched_barrier(0);
    if (t + 2 < NT){
      #pragma unroll
      for (int l = 0; l < L; ++l)
        dp_issue<BM, BN>(A, Bt, curb, K, m0, n0, (t + 2) << 6, wave, lane, l);
    }
  }

  #pragma unroll
  for (int i = 0; i < FR; ++i){
    #pragma unroll
    for (int j = 0; j < FC; ++j){
      #pragma unroll
      for (int rr = 0; rr < 4; ++rr){
        int row = m0 + wr * WM + i * 16 + lg * 4 + rr;
        int col = n0 + wc * WN + j * 16 + la;
        float v = acc[i][j][rr];
        size_t idx = (size_t)row * N + col;
        if (EPI == EPI_F32){
          outF[idx] = v;
        } else if (EPI == EPI_RESID){
          outF[idx] = v + resid[idx];
        } else { // EPI_QKV: q scaled by (1/32)*log2(e) for exp2-domain softmax
          int which = col >> 10;
          int hh = (col & 1023) >> 6;
          int d = col & 63;
          int bb = row >> 11, tt = row & 2047;
          size_t o = (((size_t)(bb * 16 + hh) * 2048) + tt) * 64 + d;
          if (which == 0)      qb[o] = f2bf(v * 0.045084220f);
          else if (which == 1) kb[o] = f2bf(v);
          else                 vb[o] = f2bf(v);
        }
      }
    }
  }
}

// ---------------- fused W&V GEMM + SwiGLU gate -----------------------------
static __device__ __forceinline__ void wv_issue(
    const short* __restrict__ A, const short* __restrict__ Bw, const short* __restrict__ Bv,
    short* __restrict__ lbuf, int K, int m0, int n0, int k0,
    int wave, int lane, int l)
{
  int g = (l * 8 + wave) * 64 + lane;     // 0..3071
  const short* src;
  if (g < 1024){
    int row = g >> 3, cc = g & 7;
    src = A + (size_t)(m0 + row) * K + k0 + ((cc ^ (row & 7)) << 3);
  } else if (g < 2048){
    int gb = g - 1024;
    int row = gb >> 3, cc = gb & 7;
    src = Bw + (size_t)(n0 + row) * K + k0 + ((cc ^ (row & 7)) << 3);
  } else {
    int gb = g - 2048;
    int row = gb >> 3, cc = gb & 7;
    src = Bv + (size_t)(n0 + row) * K + k0 + ((cc ^ (row & 7)) << 3);
  }
  __builtin_amdgcn_global_load_lds((const __attribute__((address_space(1))) void*)src,
                                   (__attribute__((address_space(3))) void*)(lbuf + (size_t)g * 8),
                                   16, 0, 0);
}

__global__ __launch_bounds__(512, 2) void gemm_wv_kernel(
    const short* __restrict__ A, const short* __restrict__ Bw, const short* __restrict__ Bv,
    int M, int N, int K, short* __restrict__ outGated)
{
  __shared__ short lds[2][384 * 64];
  const int tid = threadIdx.x, lane = tid & 63, wave = tid >> 6;
  const int wr = wave >> 2, wc = wave & 3;
  const int la = lane & 15, lg = lane >> 4;

  int nbn = N >> 7;
  int nwg = (M >> 7) * nbn;
  int bid = blockIdx.x;
  int wg = ((nwg & 7) == 0) ? ((bid & 7) * (nwg >> 3) + (bid >> 3)) : bid;
  int m0 = (wg / nbn) << 7, n0 = (wg % nbn) << 7;

  f32x4 accW[4][2], accV[4][2];
  #pragma unroll
  for (int i = 0; i < 4; ++i)
    #pragma unroll
    for (int j = 0; j < 2; ++j){
      accW[i][j] = f32x4{0.f, 0.f, 0.f, 0.f};
      accV[i][j] = f32x4{0.f, 0.f, 0.f, 0.f};
    }

  const int NT = K >> 6;

  #pragma unroll
  for (int l = 0; l < 6; ++l) wv_issue(A, Bw, Bv, lds[0], K, m0, n0, 0,  wave, lane, l);
  #pragma unroll
  for (int l = 0; l < 6; ++l) wv_issue(A, Bw, Bv, lds[1], K, m0, n0, 64, wave, lane, l);

  for (int t = 0; t < NT; ++t){
    short* curb = lds[t & 1];
    if (t + 1 < NT) asm volatile("s_waitcnt vmcnt(6)" ::: "memory");
    else            asm volatile("s_waitcnt vmcnt(0)" ::: "memory");
    __builtin_amdgcn_s_barrier();
    __builtin_amdgcn_sched_barrier(0);

    bf16x8 af[4][2], bw[2][2], bv[2][2];
    #pragma unroll
    for (int ii = 0; ii < 4; ++ii){
      int r = wr * 64 + ii * 16 + la;
      #pragma unroll
      for (int ks = 0; ks < 2; ++ks)
        af[ii][ks] = *(const bf16x8*)(curb + r * 64 + (((ks * 4 + lg) ^ (r & 7)) << 3));
    }
    #pragma unroll
    for (int jc = 0; jc < 2; ++jc){
      int rb = wc * 32 + jc * 16 + la;
      #pragma unroll
      for (int ks = 0; ks < 2; ++ks){
        bw[jc][ks] = *(const bf16x8*)(curb +  8192 + rb * 64 + (((ks * 4 + lg) ^ (rb & 7)) << 3));
        bv[jc][ks] = *(const bf16x8*)(curb + 16384 + rb * 64 + (((ks * 4 + lg) ^ (rb & 7)) << 3));
      }
    }
    __builtin_amdgcn_s_setprio(1);
    #pragma unroll
    for (int ii = 0; ii < 4; ++ii)
      #pragma unroll
      for (int jc = 0; jc < 2; ++jc){
        accW[ii][jc] = __builtin_amdgcn_mfma_f32_16x16x32_bf16(af[ii][0], bw[jc][0], accW[ii][jc], 0, 0, 0);
        accW[ii][jc] = __builtin_amdgcn_mfma_f32_16x16x32_bf16(af[ii][1], bw[jc][1], accW[ii][jc], 0, 0, 0);
        accV[ii][jc] = __builtin_amdgcn_mfma_f32_16x16x32_bf16(af[ii][0], bv[jc][0], accV[ii][jc], 0, 0, 0);
        accV[ii][jc] = __builtin_amdgcn_mfma_f32_16x16x32_bf16(af[ii][1], bv[jc][1], accV[ii][jc], 0, 0, 0);
      }
    __builtin_amdgcn_s_setprio(0);
    __builtin_amdgcn_sched_barrier(0);
    __builtin_amdgcn_s_barrier();
    __builtin_amdgcn_sched_barrier(0);
    if (t + 2 < NT){
      #pragma unroll
      for (int l = 0; l < 6; ++l)
        wv_issue(A, Bw, Bv, curb, K, m0, n0, (t + 2) << 6, wave, lane, l);
    }
  }

  #pragma unroll
  for (int i = 0; i < 4; ++i){
    #pragma unroll
    for (int j = 0; j < 2; ++j){
      #pragma unroll
      for (int rr = 0; rr < 4; ++rr){
        int row = m0 + wr * 64 + i * 16 + lg * 4 + rr;
        int col = n0 + wc * 32 + j * 16 + la;
        float gg = accW[i][j][rr];
        float vv = accV[i][j][rr];
        float s = gg / (1.f + __expf(-gg));
        outGated[(size_t)row * N + col] = f2bf(s * vv);
      }
    }
  }
}

// ---------------- flash attention: R16 structure, DIAGONAL-FIRST kv --------
#define CBASE(r) ((float)(((r) & 3) + 8 * ((r) >> 2)))
#define CBI(r)   ((((r) & 3) + 8 * ((r) >> 2)))

#define KVLOAD(KF, VF, T_)                                                      \
  do {                                                                          \
    _Pragma("unroll")                                                           \
    for (int ks = 0; ks < 4; ++ks)                                              \
      KF[ks] = *(const bf16x8*)(Kg + ((size_t)((T_) * 32 + q32)) * 64 + ks * 16 + hi * 8); \
    _Pragma("unroll")                                                           \
    for (int dk = 0; dk < 4; ++dk)                                              \
      VF[dk] = *(const bf16x8*)(Vt + ((size_t)((dk >> 1) * 32 + q32)) * 2048 + (T_) * 32 + (dk & 1) * 16 + hi * 8); \
  } while (0)

#define PROC(CK, CV, T_, DOPF, NK, NV)                                          \
  do {                                                                          \
    f32x16 sS;                                                                  \
    _Pragma("unroll") for (int i = 0; i < 16; ++i) sS[i] = 0.f;                 \
    sS = __builtin_amdgcn_mfma_f32_32x32x16_bf16(CK[0], qf[0], sS, 0, 0, 0);    \
    sS = __builtin_amdgcn_mfma_f32_32x32x16_bf16(CK[1], qf[1], sS, 0, 0, 0);    \
    sS = __builtin_amdgcn_mfma_f32_32x32x16_bf16(CK[2], qf[2], sS, 0, 0, 0);    \
    sS = __builtin_amdgcn_mfma_f32_32x32x16_bf16(CK[3], qf[3], sS, 0, 0, 0);    \
    if (DOPF) KVLOAD(NK, NV, (T_) - 2);                                         \
    float bb2 = slope2 * (float)((T_) * 32 + 4 * hi - qpos);                    \
    float sc[16];                                                               \
    _Pragma("unroll")                                                           \
    for (int r = 0; r < 16; ++r) sc[r] = (sS[r] + bb2) + slope2 * CBASE(r);     \
    if ((T_) == j){                                                             \
      _Pragma("unroll")                                                         \
      for (int r = 0; r < 16; ++r)                                              \
        sc[r] = (CBI(r) + 4 * hi <= q32) ? sc[r] : -1e30f;                      \
    }                                                                           \
    float t8[8], t4[4];                                                         \
    _Pragma("unroll") for (int i = 0; i < 8; ++i) t8[i] = fmaxf(sc[i], sc[i + 8]); \
    _Pragma("unroll") for (int i = 0; i < 4; ++i) t4[i] = fmaxf(t8[i], t8[i + 4]); \
    float mx = fmaxf(fmaxf(t4[0], t4[1]), fmaxf(t4[2], t4[3]));                 \
    mx = fmaxf(mx, __shfl_xor(mx, 32, 64));                                     \
    if (!__all(mx <= m_run + 8.f)){                                             \
      float mnew = fmaxf(m_run, mx);                                            \
      float aL = exp2f(m_run - mnew);                                           \
      l_run *= aL;                                                              \
      m_run = mnew;                                                             \
      _Pragma("unroll")                                                         \
      for (int r = 0; r < 16; ++r){                                             \
        float aq = __shfl(aL, CBI(r) + 4 * hi, 64);                             \
        o0[r] *= aq; o1[r] *= aq;                                               \
      }                                                                         \
    }                                                                           \
    float pr[16];                                                               \
    _Pragma("unroll")                                                           \
    for (int r = 0; r < 16; ++r) pr[r] = exp2f(sc[r] - m_run);                  \
    _Pragma("unroll") for (int i = 0; i < 8; ++i) t8[i] = pr[i] + pr[i + 8];    \
    _Pragma("unroll") for (int i = 0; i < 4; ++i) t4[i] = t8[i] + t8[i + 4];    \
    float ps = (t4[0] + t4[1]) + (t4[2] + t4[3]);                               \
    ps += __shfl_xor(ps, 32, 64);                                               \
    l_run += ps;                                                                \
    unsigned c0 = cvtpk(pr[0], pr[1]),   c1 = cvtpk(pr[2], pr[3]);              \
    unsigned c2 = cvtpk(pr[4], pr[5]),   c3 = cvtpk(pr[6], pr[7]);              \
    unsigned c4 = cvtpk(pr[8], pr[9]),   c5 = cvtpk(pr[10], pr[11]);            \
    unsigned c6 = cvtpk(pr[12], pr[13]), c7 = cvtpk(pr[14], pr[15]);            \
    unsigned x0 = (unsigned)__shfl_xor((int)c0, 32, 64), x1 = (unsigned)__shfl_xor((int)c1, 32, 64); \
    unsigned x2 = (unsigned)__shfl_xor((int)c2, 32, 64), x3 = (unsigned)__shfl_xor((int)c3, 32, 64); \
    unsigned x4 = (unsigned)__shfl_xor((int)c4, 32, 64), x5 = (unsigned)__shfl_xor((int)c5, 32, 64); \
    unsigned x6 = (unsigned)__shfl_xor((int)c6, 32, 64), x7 = (unsigned)__shfl_xor((int)c7, 32, 64); \
    union { unsigned u[4]; bf16x8 v; } pa0u, pa1u;                              \
    pa0u.u[0] = hi ? x2 : c0;  pa0u.u[1] = hi ? x3 : c1;                        \
    pa0u.u[2] = hi ? c2 : x0;  pa0u.u[3] = hi ? c3 : x1;                        \
    pa1u.u[0] = hi ? x6 : c4;  pa1u.u[1] = hi ? x7 : c5;                        \
    pa1u.u[2] = hi ? c6 : x4;  pa1u.u[3] = hi ? c7 : x5;                        \
    o0 = __builtin_amdgcn_mfma_f32_32x32x16_bf16(pa0u.v, CV[0], o0, 0, 0, 0);   \
    o0 = __builtin_amdgcn_mfma_f32_32x32x16_bf16(pa1u.v, CV[1], o0, 0, 0, 0);   \
    o1 = __builtin_amdgcn_mfma_f32_32x32x16_bf16(pa0u.v, CV[2], o1, 0, 0, 0);   \
    o1 = __builtin_amdgcn_mfma_f32_32x32x16_bf16(pa1u.v, CV[3], o1, 0, 0, 0);   \
  } while (0)

__global__ __launch_bounds__(512) void attn_kernel(
    const short* __restrict__ qb, const short* __restrict__ kb,
    const short* __restrict__ vtb, short* __restrict__ concat)
{
  const int T = 2048;
  int id = blockIdx.x;                 // 256 blocks
  int grp = id & 7;                    // XCD-ish group: bh {4*grp .. 4*grp+3}
  int p   = id >> 3;                   // q-pair 0..31
  int wid = threadIdx.x >> 6;
  int e   = wid & 3;                   // task slot (bh within group)
  int s   = wid >> 2;                  // kv parity 0/1
  int bh = grp * 4 + e;
  int lane = threadIdx.x & 63;
  int q32 = lane & 31;
  int hi  = lane >> 5;
  int h = bh & 15, b = bh >> 4;

  __shared__ float partLDS[4][16][64][2];   // [slot][r2][lane][pair] 32KB
  __shared__ float mlLDS[4][64][2];         // [slot][lane][m,l]      2KB

  const short* Q  = qb  + (size_t)bh * T * 64;
  const short* Kg = kb  + (size_t)bh * T * 64;  // [t][d]
  const short* Vt = vtb + (size_t)bh * 64 * T;  // [d][t]

  float slope2 = exp2f(-0.5f * (float)(h + 1)) * 1.44269504f;

  for (int task = 0; task < 2; ++task){
    int j = task ? (63 - p) : p;
    int q0 = j * 32;
    int qpos = q0 + q32;

    bf16x8 qf[4];
    #pragma unroll
    for (int ks = 0; ks < 4; ++ks)
      qf[ks] = *(const bf16x8*)(Q + (size_t)qpos * 64 + ks * 16 + hi * 8);

    f32x16 o0, o1;
    #pragma unroll
    for (int i = 0; i < 16; ++i){ o0[i] = 0.f; o1[i] = 0.f; }
    float m_run = -1e30f, l_run = 0.f;

    if (s <= j){
      // descending kv: start at largest tile of this parity (diagonal side)
      int t0 = j - ((j - s) & 1);
      bf16x8 kA[4], vA[4], kB[4], vB[4];
      KVLOAD(kA, vA, t0);
      int t = t0;
      while (1){
        PROC(kA, vA, t, (t - 2 >= s), kB, vB);
        t -= 2; if (t < s) break;
        PROC(kB, vB, t, (t - 2 >= s), kA, vA);
        t -= 2; if (t < s) break;
      }
    }

    if (s == 0){
      #pragma unroll
      for (int r2 = 0; r2 < 8; ++r2){
        partLDS[e][r2][lane][0]     = o0[2 * r2];
        partLDS[e][r2][lane][1]     = o0[2 * r2 + 1];
        partLDS[e][r2 + 8][lane][0] = o1[2 * r2];
        partLDS[e][r2 + 8][lane][1] = o1[2 * r2 + 1];
      }
      mlLDS[e][lane][0] = m_run;
      mlLDS[e][lane][1] = l_run;
    }
    __syncthreads();
    if (s == 1){
      float mE = mlLDS[e][lane][0];
      float lE = mlLDS[e][lane][1];
      float mS = fmaxf(mE, m_run);
      float aE = exp2f(mE - mS);
      float aO = exp2f(m_run - mS);
      float lT = aE * lE + aO * l_run;
      float linv = 1.f / lT;
      float fE = aE * linv;
      float fO = aO * linv;
      #pragma unroll
      for (int r = 0; r < 16; ++r){
        int crow = CBI(r) + 4 * hi;
        float fEr = __shfl(fE, crow, 64);
        float fOr = __shfl(fO, crow, 64);
        float oE0 = partLDS[e][r >> 1][lane][r & 1];
        float oE1 = partLDS[e][8 + (r >> 1)][lane][r & 1];
        size_t base = ((size_t)(b * 2048 + q0 + crow)) * 1024 + h * 64;
        concat[base + q32]      = f2bf(fEr * oE0 + fOr * o0[r]);
        concat[base + 32 + q32] = f2bf(fEr * oE1 + fOr * o1[r]);
      }
    }
    __syncthreads();
  }
}

extern "C" void kernel_launch(void* const* d_in, const int* in_sizes, int n_in,
                              void* d_out, int out_size, void* d_ws, size_t ws_size,
                              hipStream_t stream)
{
  (void)in_sizes; (void)n_in; (void)out_size; (void)ws_size;
  const float* x     = (const float*)d_in[0];
  const float* g1    = (const float*)d_in[1];
  const float* w_qkv = (const float*)d_in[2];
  const float* w_o   = (const float*)d_in[3];
  const float* g2    = (const float*)d_in[4];
  const float* W     = (const float*)d_in[5];
  const float* V     = (const float*)d_in[6];
  const float* W2    = (const float*)d_in[7];
  float* out = (float*)d_out;

  char* wsb = (char*)d_ws;
  size_t off = 0;
  auto alloc = [&](size_t bytes) -> void* {
    void* p = wsb + off;
    off += (bytes + 255) & ~(size_t)255;
    return p;
  };
  short* wqkvT = (short*)alloc((size_t)3072 * 1024 * 2);
  short* woT   = (short*)alloc((size_t)1024 * 1024 * 2);
  short* WT    = (short*)alloc((size_t)2816 * 1024 * 2);
  short* VT    = (short*)alloc((size_t)2816 * 1024 * 2);
  short* W2T   = (short*)alloc((size_t)1024 * 2816 * 2);
  short* h1    = (short*)alloc((size_t)4096 * 1024 * 2);
  short* qbuf  = (short*)alloc((size_t)4096 * 1024 * 2);
  short* kbuf  = (short*)alloc((size_t)4096 * 1024 * 2);
  short* vbuf  = (short*)alloc((size_t)4096 * 1024 * 2); // [B,H,T,64]
  short* vtbuf = (short*)alloc((size_t)4096 * 1024 * 2); // [B,H,64,T]
  short* conc  = (short*)alloc((size_t)4096 * 1024 * 2);
  float* x2    = (float*)alloc((size_t)4096 * 1024 * 4);
  short* h2    = (short*)alloc((size_t)4096 * 1024 * 2);
  short* gated = (short*)alloc((size_t)4096 * 2816 * 2);

  dim3 tb(32, 8);
  // fused prologue: five weight transposes + rmsnorm1 in one launch
  hipLaunchKernelGGL(prologue_kernel, dim3(16640), tb, 0, stream,
                     w_qkv, w_o, W, V, W2, wqkvT, woT, WT, VT, W2T,
                     x, g1, h1);

  hipLaunchKernelGGL((gemm_dp_kernel<128, 128, EPI_QKV>), dim3(768), dim3(512), 0, stream,
                     h1, wqkvT, 4096, 3072, 1024,
                     (float*)nullptr, (short*)nullptr, (const float*)nullptr,
                     qbuf, kbuf, vbuf);

  hipLaunchKernelGGL(transpose_bb_kernel, dim3(64, 2, 32), tb, 0, stream, vbuf, vtbuf);

  hipLaunchKernelGGL(attn_kernel, dim3(256), dim3(512), 0, stream, qbuf, kbuf, vtbuf, conc);

  hipLaunchKernelGGL((gemm_dp_kernel<128, 128, EPI_RESID>), dim3(256), dim3(512), 0, stream,
                     conc, woT, 4096, 1024, 1024,
                     x2, (short*)nullptr, x,
                     (short*)nullptr, (short*)nullptr, (short*)nullptr);

  hipLaunchKernelGGL(rmsnorm_kernel, dim3(4096), dim3(256), 0, stream, x2, g2, h2);

  hipLaunchKernelGGL(gemm_wv_kernel, dim3(704), dim3(512), 0, stream,
                     h2, WT, VT, 4096, 2816, 1024, gated);

  hipLaunchKernelGGL((gemm_dp_kernel<128, 128, EPI_RESID>), dim3(256), dim3(512), 0, stream,
                     gated, W2T, 4096, 1024, 2816,
                     out, (short*)nullptr, x2,
                     (short*)nullptr, (short*)nullptr, (short*)nullptr);
}